// Round 10
// baseline (912.810 us; speedup 1.0000x reference)
//
#include <hip/hip_runtime.h>

#define N_NODES 100000
#define N_EDGES 1600000
#define CAP 60            // per-node edge-list capacity; P(deg>60) ~ 1e-10

typedef unsigned short u16;
typedef short s16x8 __attribute__((ext_vector_type(8)));
typedef float f32x4 __attribute__((ext_vector_type(4)));
typedef unsigned u32x2 __attribute__((ext_vector_type(2)));
typedef unsigned u32x4 __attribute__((ext_vector_type(4)));

__device__ __forceinline__ u16 f2bf(float f) {   // software RNE, proven R2-R9
    union { float f; unsigned int i; } c;
    c.f = f;
    unsigned int u = c.i;
    return (u16)((u + 0x7fffu + ((u >> 16) & 1u)) >> 16);
}

// packed f32x2 -> bf16x2 (software RNE; hand-written v_cvt_pk_bf16_f32 asm
// corrupted values in R5 — m240. NT loads regressed in R8. Plain code only.)
__device__ __forceinline__ unsigned pkbf(float lo, float hi) {
    return (unsigned)f2bf(lo) | ((unsigned)f2bf(hi) << 16);
}

__device__ __forceinline__ f32x4 mfma16(s16x8 a, s16x8 b, f32x4 c) {
    return __builtin_amdgcn_mfma_f32_16x16x32_bf16(a, b, c, 0, 0, 0);
}

// ---------------------------------------------------------------------------
// Detect edge_index width: int64 (values < 2^31) => odd int32 words all zero.
// ---------------------------------------------------------------------------
__global__ __launch_bounds__(256) void detect_idx(const int* __restrict__ eidx,
                                                  int* __restrict__ flag)
{
    __shared__ int snz;
    const int tid = threadIdx.x;
    if (tid == 0) snz = 0;
    __syncthreads();
    int nz = 0;
    #pragma unroll
    for (int k = 0; k < 8; ++k) {
        long pos = 1 + 2 * ((long)tid * 781 + k * 97);
        if (pos < 2L * N_EDGES) nz |= (eidx[pos] != 0);
    }
    if (nz) snz = 1;
    __syncthreads();
    if (tid == 0) *flag = snz ? 0 : 1;
}

// ---------------------------------------------------------------------------
// CSR-ish bucket build: cnt[dst]++, idx[dst*CAP+slot] = e  (int atomics only)
// ---------------------------------------------------------------------------
__global__ __launch_bounds__(256) void build_csr(
    const void* __restrict__ eidx_raw, const int* __restrict__ flag64,
    int* __restrict__ cnt, int* __restrict__ idx)
{
    const long e = (long)blockIdx.x * 256 + threadIdx.x;
    if (e >= N_EDGES) return;
    const int f64 = *flag64;
    int d = f64 ? (int)((const long long*)eidx_raw)[(long)N_EDGES + e]
                : ((const int*)eidx_raw)[(long)N_EDGES + e];
    d = min(max(d, 0), N_NODES - 1);
    int slot = atomicAdd(&cnt[d], 1);
    if (slot < CAP) idx[(long)d * CAP + slot] = (int)e;
}

// ---------------------------------------------------------------------------
// Weight repack (f32 -> bf16) into MFMA B-fragment order:
//   packed[((ks*N + n)*4 + kg)*8 + j] = (bf16)W[(ks*32 + kg*8 + j)*N + n]
// ---------------------------------------------------------------------------
__global__ __launch_bounds__(256) void pack_w(
    const float* __restrict__ eW1, const float* __restrict__ eW2,
    const float* __restrict__ nW1, const float* __restrict__ nW2,
    u16* __restrict__ W1p, u16* __restrict__ W2p,
    u16* __restrict__ nW1p, u16* __restrict__ nW2p)
{
    int t = blockIdx.x * 256 + threadIdx.x;
    if (t < 24576) {                               // eW1 [192][128]
        int j = t & 7, kg = (t >> 3) & 3, n = (t >> 5) & 127, ks = t >> 12;
        W1p[t] = f2bf(eW1[(ks * 32 + kg * 8 + j) * 128 + n]);
    } else if (t < 24576 + 8192) {                 // eW2 [128][64]
        int u = t - 24576;
        int j = u & 7, kg = (u >> 3) & 3, n = (u >> 5) & 63, ks = u >> 11;
        W2p[u] = f2bf(eW2[(ks * 32 + kg * 8 + j) * 64 + n]);
    } else if (t < 24576 + 8192 + 16384) {         // nW1 [128][128]
        int u = t - (24576 + 8192);
        int j = u & 7, kg = (u >> 3) & 3, n = (u >> 5) & 127, ks = u >> 12;
        nW1p[u] = f2bf(nW1[(ks * 32 + kg * 8 + j) * 128 + n]);
    } else if (t < 24576 + 8192 + 16384 + 8192) {  // nW2 [128][64]
        int u = t - (24576 + 8192 + 16384);
        int j = u & 7, kg = (u >> 3) & 3, n = (u >> 5) & 63, ks = u >> 11;
        nW2p[u] = f2bf(nW2[(ks * 32 + kg * 8 + j) * 64 + n]);
    }
}

#define LDH  136   // node kernel hidden tile stride (overlays A)
#define LDC  68    // node kernel f32 pre-LN stride (overlays A)
#define HTS  136   // edge wave-private Ht stride (u16): 272B = 17*16 -> b128-aligned
#define CTS  68    // edge wave-private Ct stride (f32): 272B

// ---------------------------------------------------------------------------
// Edge update, wave-independent: each wave owns 16 edges end-to-end; NO block
// barriers (R9's 6-barrier lockstep left all pipes <30% busy). A-fragments
// gathered straight from global into registers (same slices the old LDS reads
// produced); H transposed through 4352B wave-private LDS with wave_barrier
// fences; LN via 4-lane shuffle on wave-private Ct overlay. 16 waves/CU all
// issuing memory continuously. R7 lesson: watch WRITE_SIZE for spill.
// ---------------------------------------------------------------------------
__global__ __launch_bounds__(256, 4) void edge_kernel(
    const float* __restrict__ x, const float* __restrict__ ea,
    const void* __restrict__ eidx_raw, const int* __restrict__ flag64,
    const u16* __restrict__ W1p, const float* __restrict__ eb1,
    const u16* __restrict__ W2p, const float* __restrict__ eb2,
    const float* __restrict__ eg, const float* __restrict__ ebt,
    float* __restrict__ out_e)
{
    __shared__ __align__(16) u16 HT[4][2176];   // per-wave 4352B: Ht[16][HTS] bf16 / Ct[16][CTS] f32 overlay

    const int tid = threadIdx.x;
    const int lane = tid & 63;
    const int wv = tid >> 6;
    const int l15 = lane & 15;
    const int l4 = lane >> 4;
    u16* Ht = &HT[wv][0];
    float* Ct = (float*)&HT[wv][0];

    const long e0 = (long)blockIdx.x * 64 + (long)wv * 16;
    const int f64 = *flag64;

    // ---- per-lane edge indices (l15 = row of the M=16 tile) ----
    const long er = e0 + l15;
    int srcI, dstI;
    if (f64) {
        srcI = (int)((const long long*)eidx_raw)[er];
        dstI = (int)((const long long*)eidx_raw)[N_EDGES + er];
    } else {
        srcI = ((const int*)eidx_raw)[er];
        dstI = ((const int*)eidx_raw)[N_EDGES + er];
    }
    srcI = min(max(srcI, 0), N_NODES - 1);
    dstI = min(max(dstI, 0), N_NODES - 1);
    const float* xs  = x + (long)srcI * 64;
    const float* xd  = x + (long)dstI * 64;
    const float* eap = ea + er * 64;

    // ---- A-fragments direct from global: af[ks] = input[l15][ks*32+l4*8..+7] ----
    s16x8 af[6];
    #pragma unroll
    for (int ks = 0; ks < 6; ++ks) {
        const float* bp = (ks < 2 ? xs : (ks < 4 ? xd : eap)) + (ks & 1) * 32 + l4 * 8;
        f32x4 v0 = *(const f32x4*)bp;
        f32x4 v1 = *(const f32x4*)(bp + 4);
        union { u32x4 u; s16x8 s; } cv;
        cv.u[0] = pkbf(v0[0], v0[1]); cv.u[1] = pkbf(v0[2], v0[3]);
        cv.u[2] = pkbf(v1[0], v1[1]); cv.u[3] = pkbf(v1[2], v1[3]);
        af[ks] = cv.s;
    }

    // ---- GEMM1: M=16, N=128, K=192 (ks-outer: 8 independent MFMA chains) ----
    f32x4 acc1[8] = {};
    #pragma unroll
    for (int ks = 0; ks < 6; ++ks) {
        #pragma unroll
        for (int nt = 0; nt < 8; ++nt) {
            s16x8 b = *(const s16x8*)(W1p + ((size_t)(ks * 128 + nt * 16 + l15) * 4 + l4) * 8);
            acc1[nt] = mfma16(af[ks], b, acc1[nt]);
        }
    }

    // ---- bias + relu -> Ht (wave-private; C/D layout row=l4*4+r, col=nt*16+l15) ----
    #pragma unroll
    for (int nt = 0; nt < 8; ++nt) {
        float b = eb1[nt * 16 + l15];
        #pragma unroll
        for (int r = 0; r < 4; ++r) {
            float v = fmaxf(acc1[nt][r] + b, 0.f);
            Ht[(l4 * 4 + r) * HTS + nt * 16 + l15] = f2bf(v);
        }
    }
    __builtin_amdgcn_wave_barrier();   // order ds_write -> ds_read within wave

    // ---- GEMM2: M=16, N=64, K=128; A from Ht (transposed view) ----
    s16x8 a2[4];
    #pragma unroll
    for (int ks2 = 0; ks2 < 4; ++ks2)
        a2[ks2] = *(const s16x8*)&Ht[l15 * HTS + ks2 * 32 + l4 * 8];
    f32x4 acc2[4] = {};
    #pragma unroll
    for (int ks2 = 0; ks2 < 4; ++ks2) {
        #pragma unroll
        for (int nt2 = 0; nt2 < 4; ++nt2) {
            s16x8 b2 = *(const s16x8*)(W2p + ((size_t)(ks2 * 64 + nt2 * 16 + l15) * 4 + l4) * 8);
            acc2[nt2] = mfma16(a2[ks2], b2, acc2[nt2]);
        }
    }
    __builtin_amdgcn_wave_barrier();   // Ht reads done; Ct overlay writable

    // ---- C2 + bias -> Ct (f32, overlays Ht) ----
    #pragma unroll
    for (int nt2 = 0; nt2 < 4; ++nt2) {
        float b = eb2[nt2 * 16 + l15];
        #pragma unroll
        for (int r = 0; r < 4; ++r)
            Ct[(l4 * 4 + r) * CTS + nt2 * 16 + l15] = acc2[nt2][r] + b;
    }
    __builtin_amdgcn_wave_barrier();

    // ---- LN + residual (f32 re-read, L1-hot from af build) + store ----
    {
        const int row16 = lane >> 2;     // 0..15
        const int q = lane & 3;
        const float* cp = &Ct[row16 * CTS + q * 16];
        float vv[16];
        #pragma unroll
        for (int i = 0; i < 4; ++i) {
            f32x4 t = *(const f32x4*)(cp + i * 4);
            vv[i * 4 + 0] = t[0]; vv[i * 4 + 1] = t[1];
            vv[i * 4 + 2] = t[2]; vv[i * 4 + 3] = t[3];
        }
        float s = 0.f, ss = 0.f;
        #pragma unroll
        for (int i = 0; i < 16; ++i) { s += vv[i]; ss += vv[i] * vv[i]; }
        s  += __shfl_xor(s, 1);  s  += __shfl_xor(s, 2);
        ss += __shfl_xor(ss, 1); ss += __shfl_xor(ss, 2);
        const float mu = s * (1.0f / 64.0f);
        const float var = ss * (1.0f / 64.0f) - mu * mu;
        const float rs = rsqrtf(var + 1e-5f);
        const long eo = e0 + row16;
        const float* rp = ea + eo * 64 + q * 16;
        float* op = out_e + eo * 64 + q * 16;
        #pragma unroll
        for (int i4 = 0; i4 < 4; ++i4) {
            f32x4 res = *(const f32x4*)(rp + i4 * 4);
            f32x4 o;
            #pragma unroll
            for (int j = 0; j < 4; ++j) {
                const int c = q * 16 + i4 * 4 + j;
                o[j] = (vv[i4 * 4 + j] - mu) * rs * eg[c] + ebt[c] + res[j];
            }
            *(f32x4*)(op + i4 * 4) = o;
        }
    }
}

// ---------------------------------------------------------------------------
// Node update: 64 nodes/block, 256 threads, single LDS buffer (Hs/C2 overlay
// A) -> 17.4KB. Aggregation by CSR gather from out_e (plain loads; NT
// regressed in R8). Unchanged from R9.
// ---------------------------------------------------------------------------
__global__ __launch_bounds__(256, 6) void node_kernel(
    const float* __restrict__ x, const float* __restrict__ out_e,
    const int* __restrict__ cnt, const int* __restrict__ idx,
    const u16* __restrict__ W1p, const float* __restrict__ nb1,
    const u16* __restrict__ W2p, const float* __restrict__ nb2,
    const float* __restrict__ ng, const float* __restrict__ nbt,
    float* __restrict__ out_x)
{
    __shared__ __align__(16) u16 A[64 * LDH];    // Hs and C2 overlay
    u16* Hs   = A;
    float* C2 = (float*)A;

    const int tid = threadIdx.x;
    const int lane = tid & 63;
    const int w = tid >> 6;
    const int l15 = lane & 15;
    const int l4 = lane >> 4;
    const int n0 = blockIdx.x * 64;

    // ---- gather-aggregate: 4 threads/node, thread q -> cols q*16..+15 ----
    const int lrow = tid >> 2;
    const int lq = tid & 3;
    {
        int n = n0 + lrow;
        if (n >= N_NODES) n = N_NODES - 1;
        int c = cnt[n];
        if (c > CAP) c = CAP;
        const int* ip = idx + (long)n * CAP;
        f32x4 s0 = {}, s1 = {}, s2 = {}, s3 = {};
        int j = 0;
        for (; j + 4 <= c; j += 4) {
            int ev0 = ip[j], ev1 = ip[j + 1], ev2 = ip[j + 2], ev3 = ip[j + 3];
            const float* p0 = out_e + (long)ev0 * 64 + lq * 16;
            const float* p1 = out_e + (long)ev1 * 64 + lq * 16;
            const float* p2 = out_e + (long)ev2 * 64 + lq * 16;
            const float* p3 = out_e + (long)ev3 * 64 + lq * 16;
            f32x4 a00 = *(const f32x4*)(p0);     f32x4 a01 = *(const f32x4*)(p0 + 4);
            f32x4 a02 = *(const f32x4*)(p0 + 8); f32x4 a03 = *(const f32x4*)(p0 + 12);
            f32x4 a10 = *(const f32x4*)(p1);     f32x4 a11 = *(const f32x4*)(p1 + 4);
            f32x4 a12 = *(const f32x4*)(p1 + 8); f32x4 a13 = *(const f32x4*)(p1 + 12);
            f32x4 a20 = *(const f32x4*)(p2);     f32x4 a21 = *(const f32x4*)(p2 + 4);
            f32x4 a22 = *(const f32x4*)(p2 + 8); f32x4 a23 = *(const f32x4*)(p2 + 12);
            f32x4 a30 = *(const f32x4*)(p3);     f32x4 a31 = *(const f32x4*)(p3 + 4);
            f32x4 a32 = *(const f32x4*)(p3 + 8); f32x4 a33 = *(const f32x4*)(p3 + 12);
            s0 += a00 + a10 + a20 + a30;
            s1 += a01 + a11 + a21 + a31;
            s2 += a02 + a12 + a22 + a32;
            s3 += a03 + a13 + a23 + a33;
        }
        for (; j < c; ++j) {
            int ev = ip[j];
            const float* p = out_e + (long)ev * 64 + lq * 16;
            s0 += *(const f32x4*)(p);
            s1 += *(const f32x4*)(p + 4);
            s2 += *(const f32x4*)(p + 8);
            s3 += *(const f32x4*)(p + 12);
        }
        u16* ap = &A[lrow * LDH + 64 + lq * 16];
        u32x2 o;
        o[0] = pkbf(s0[0], s0[1]); o[1] = pkbf(s0[2], s0[3]);
        *(u32x2*)(ap) = o;
        o[0] = pkbf(s1[0], s1[1]); o[1] = pkbf(s1[2], s1[3]);
        *(u32x2*)(ap + 4) = o;
        o[0] = pkbf(s2[0], s2[1]); o[1] = pkbf(s2[2], s2[3]);
        *(u32x2*)(ap + 8) = o;
        o[0] = pkbf(s3[0], s3[1]); o[1] = pkbf(s3[2], s3[3]);
        *(u32x2*)(ap + 12) = o;
    }

    // ---- stage x (cols 0..63), f32 -> bf16 ----
    {
        const int s = tid & 15;
        const int rb = tid >> 4;
        #pragma unroll
        for (int p = 0; p < 4; ++p) {
            int row = p * 16 + rb;
            long gr = n0 + row;
            if (gr >= N_NODES) gr = N_NODES - 1;
            f32x4 v = *(const f32x4*)(x + gr * 64 + s * 4);
            u32x2 o;
            o[0] = pkbf(v[0], v[1]); o[1] = pkbf(v[2], v[3]);
            *(u32x2*)&A[row * LDH + s * 4] = o;
        }
    }
    __syncthreads();

    // ---- GEMM1: [64x128] @ [128x128] ----
    s16x8 bf1[4][2];
    #pragma unroll
    for (int ks = 0; ks < 4; ++ks)
        #pragma unroll
        for (int nt = 0; nt < 2; ++nt) {
            int n = 32 * w + nt * 16 + l15;
            bf1[ks][nt] = *(const s16x8*)(W1p + ((size_t)(ks * 128 + n) * 4 + l4) * 8);
        }
    f32x4 acc[4][2] = {};
    #pragma unroll
    for (int ks = 0; ks < 4; ++ks) {
        #pragma unroll
        for (int mt = 0; mt < 4; ++mt) {
            s16x8 a = *(const s16x8*)&A[(mt * 16 + l15) * LDH + ks * 32 + l4 * 8];
            #pragma unroll
            for (int nt = 0; nt < 2; ++nt)
                acc[mt][nt] = mfma16(a, bf1[ks][nt], acc[mt][nt]);
        }
    }
    __syncthreads();   // A reads done; Hs overlay writable

    #pragma unroll
    for (int nt = 0; nt < 2; ++nt) {
        int n = 32 * w + nt * 16 + l15;
        float b = nb1[n];
        #pragma unroll
        for (int mt = 0; mt < 4; ++mt) {
            float v0 = fmaxf(acc[mt][nt][0] + b, 0.f);
            float v1 = fmaxf(acc[mt][nt][1] + b, 0.f);
            float v2 = fmaxf(acc[mt][nt][2] + b, 0.f);
            float v3 = fmaxf(acc[mt][nt][3] + b, 0.f);
            unsigned w0 = pkbf(v0, v1), w1 = pkbf(v2, v3);
            int r0 = mt * 16 + l4 * 4;
            Hs[(r0 + 0) * LDH + n] = (u16)w0;
            Hs[(r0 + 1) * LDH + n] = (u16)(w0 >> 16);
            Hs[(r0 + 2) * LDH + n] = (u16)w1;
            Hs[(r0 + 3) * LDH + n] = (u16)(w1 >> 16);
        }
    }
    __syncthreads();

    // ---- GEMM2: [64x128] @ [128x64] ----
    s16x8 bf2v[4];
    #pragma unroll
    for (int ks = 0; ks < 4; ++ks)
        bf2v[ks] = *(const s16x8*)(W2p + ((size_t)(ks * 64 + 16 * w + l15) * 4 + l4) * 8);
    f32x4 acc2[4] = {};
    #pragma unroll
    for (int ks = 0; ks < 4; ++ks) {
        #pragma unroll
        for (int mt = 0; mt < 4; ++mt) {
            s16x8 a = *(const s16x8*)&Hs[(mt * 16 + l15) * LDH + ks * 32 + l4 * 8];
            acc2[mt] = mfma16(a, bf2v[ks], acc2[mt]);
        }
    }
    __syncthreads();   // Hs reads done; C2 overlay writable

    {
        int n = 16 * w + l15;
        float b = nb2[n];
        #pragma unroll
        for (int mt = 0; mt < 4; ++mt)
            #pragma unroll
            for (int r = 0; r < 4; ++r)
                C2[(mt * 16 + l4 * 4 + r) * LDC + n] = acc2[mt][r] + b;
    }
    __syncthreads();

    // ---- LayerNorm + residual(x re-read, L3-hot) + store ----
    {
        const float* cp = &C2[lrow * LDC + lq * 16];
        float vv[16];
        #pragma unroll
        for (int i = 0; i < 4; ++i) {
            f32x4 t = *(const f32x4*)(cp + i * 4);
            vv[i * 4 + 0] = t[0]; vv[i * 4 + 1] = t[1];
            vv[i * 4 + 2] = t[2]; vv[i * 4 + 3] = t[3];
        }
        float s = 0.f, ss = 0.f;
        #pragma unroll
        for (int i = 0; i < 16; ++i) { s += vv[i]; ss += vv[i] * vv[i]; }
        s  += __shfl_xor(s, 1);  s  += __shfl_xor(s, 2);
        ss += __shfl_xor(ss, 1); ss += __shfl_xor(ss, 2);
        const float mu = s * (1.0f / 64.0f);
        const float var = ss * (1.0f / 64.0f) - mu * mu;
        const float rs = rsqrtf(var + 1e-5f);
        const long gnode = n0 + lrow;
        if (gnode < N_NODES) {
            const float* rp = x + gnode * 64 + lq * 16;
            float* op = out_x + gnode * 64 + lq * 16;
            #pragma unroll
            for (int i4 = 0; i4 < 4; ++i4) {
                f32x4 res = *(const f32x4*)(rp + i4 * 4);
                f32x4 o;
                #pragma unroll
                for (int j = 0; j < 4; ++j) {
                    const int c = lq * 16 + i4 * 4 + j;
                    o[j] = (vv[i4 * 4 + j] - mu) * rs * ng[c] + nbt[c] + res[j];
                }
                *(f32x4*)(op + i4 * 4) = o;
            }
        }
    }
}

extern "C" void kernel_launch(void* const* d_in, const int* in_sizes, int n_in,
                              void* d_out, int out_size, void* d_ws, size_t ws_size,
                              hipStream_t stream) {
    const float* x   = (const float*)d_in[0];
    const float* ea  = (const float*)d_in[1];
    const void*  ei  = d_in[2];
    const float* eW1 = (const float*)d_in[3];
    const float* eb1 = (const float*)d_in[4];
    const float* eW2 = (const float*)d_in[5];
    const float* eb2 = (const float*)d_in[6];
    const float* eg  = (const float*)d_in[7];
    const float* ebt = (const float*)d_in[8];
    const float* nW1 = (const float*)d_in[9];
    const float* nb1 = (const float*)d_in[10];
    const float* nW2 = (const float*)d_in[11];
    const float* nb2 = (const float*)d_in[12];
    const float* ng  = (const float*)d_in[13];
    const float* nbt = (const float*)d_in[14];

    float* out   = (float*)d_out;
    float* out_x = out;                            // [100000, 64]
    float* out_e = out + (size_t)N_NODES * 64;     // [1600000, 64]

    // ws layout: packed weights 114688 B | flag 4 B | pad |
    //            cnt 400000 B | pad | idx 100000*CAP*4 B   (~24.5 MB total)
    u16* W1p   = (u16*)d_ws;
    u16* W2p   = W1p + 24576;
    u16* nW1p  = W2p + 8192;
    u16* nW2p  = nW1p + 16384;
    int* flag  = (int*)((char*)d_ws + 114688);
    int* cnt   = (int*)((char*)d_ws + 114944);
    int* idx   = (int*)((char*)d_ws + 515072);

    hipMemsetAsync(cnt, 0, (size_t)N_NODES * sizeof(int), stream);
    detect_idx<<<1, 256, 0, stream>>>((const int*)ei, flag);
    pack_w<<<224, 256, 0, stream>>>(eW1, eW2, nW1, nW2, W1p, W2p, nW1p, nW2p);
    build_csr<<<(N_EDGES + 255) / 256, 256, 0, stream>>>(ei, flag, cnt, idx);
    edge_kernel<<<N_EDGES / 64, 256, 0, stream>>>(x, ea, ei, flag, W1p, eb1,
                                                  W2p, eb2, eg, ebt, out_e);
    node_kernel<<<(N_NODES + 63) / 64, 256, 0, stream>>>(x, out_e, cnt, idx,
                                                         nW1p, nb1, nW2p, nb2,
                                                         ng, nbt, out_x);
}

// Round 12
// 860.980 us; speedup vs baseline: 1.0602x; 1.0602x over previous
//
#include <hip/hip_runtime.h>

#define N_NODES 100000
#define N_EDGES 1600000
#define CAP 60            // per-node edge-list capacity; P(deg>60) ~ 1e-10
#define T_TILES 4         // edge tiles (64 edges each) per block

typedef unsigned short u16;
typedef short s16x8 __attribute__((ext_vector_type(8)));
typedef float f32x4 __attribute__((ext_vector_type(4)));
typedef unsigned u32x2 __attribute__((ext_vector_type(2)));
typedef unsigned u32x4 __attribute__((ext_vector_type(4)));

__device__ __forceinline__ u16 f2bf(float f) {   // software RNE, proven R2-R11
    union { float f; unsigned int i; } c;
    c.f = f;
    unsigned int u = c.i;
    return (u16)((u + 0x7fffu + ((u >> 16) & 1u)) >> 16);
}

// packed f32x2 -> bf16x2 (software RNE). History: hand-written
// v_cvt_pk_bf16_f32 asm corrupted values (R5); NT loads regressed (R8);
// raw s_barrier pipeline raced (R11). Plain code + __syncthreads only.
__device__ __forceinline__ unsigned pkbf(float lo, float hi) {
    return (unsigned)f2bf(lo) | ((unsigned)f2bf(hi) << 16);
}

__device__ __forceinline__ f32x4 mfma16(s16x8 a, s16x8 b, f32x4 c) {
    return __builtin_amdgcn_mfma_f32_16x16x32_bf16(a, b, c, 0, 0, 0);
}

// ---------------------------------------------------------------------------
// Weight repack (f32 -> bf16) into MFMA B-fragment order; block 224 instead
// runs the edge_index width detection (int64 => odd int32 words all zero).
// ---------------------------------------------------------------------------
__global__ __launch_bounds__(256) void pack_w(
    const float* __restrict__ eW1, const float* __restrict__ eW2,
    const float* __restrict__ nW1, const float* __restrict__ nW2,
    u16* __restrict__ W1p, u16* __restrict__ W2p,
    u16* __restrict__ nW1p, u16* __restrict__ nW2p,
    const int* __restrict__ eidx, int* __restrict__ flag)
{
    if (blockIdx.x == 224) {                       // fused detect_idx
        __shared__ int snz;
        const int tid = threadIdx.x;
        if (tid == 0) snz = 0;
        __syncthreads();
        int nz = 0;
        #pragma unroll
        for (int k = 0; k < 8; ++k) {
            long pos = 1 + 2 * ((long)tid * 781 + k * 97);
            if (pos < 2L * N_EDGES) nz |= (eidx[pos] != 0);
        }
        if (nz) snz = 1;
        __syncthreads();
        if (tid == 0) *flag = snz ? 0 : 1;
        return;
    }
    int t = blockIdx.x * 256 + threadIdx.x;
    if (t < 24576) {                               // eW1 [192][128]
        int j = t & 7, kg = (t >> 3) & 3, n = (t >> 5) & 127, ks = t >> 12;
        W1p[t] = f2bf(eW1[(ks * 32 + kg * 8 + j) * 128 + n]);
    } else if (t < 24576 + 8192) {                 // eW2 [128][64]
        int u = t - 24576;
        int j = u & 7, kg = (u >> 3) & 3, n = (u >> 5) & 63, ks = u >> 11;
        W2p[u] = f2bf(eW2[(ks * 32 + kg * 8 + j) * 64 + n]);
    } else if (t < 24576 + 8192 + 16384) {         // nW1 [128][128]
        int u = t - (24576 + 8192);
        int j = u & 7, kg = (u >> 3) & 3, n = (u >> 5) & 127, ks = u >> 12;
        nW1p[u] = f2bf(nW1[(ks * 32 + kg * 8 + j) * 128 + n]);
    } else if (t < 24576 + 8192 + 16384 + 8192) {  // nW2 [128][64]
        int u = t - (24576 + 8192 + 16384);
        int j = u & 7, kg = (u >> 3) & 3, n = (u >> 5) & 63, ks = u >> 11;
        nW2p[u] = f2bf(nW2[(ks * 32 + kg * 8 + j) * 64 + n]);
    }
}

#define LDA1 200   // 64x192 bf16 input tile row stride (400B = 4-bank step)
#define LDH  136   // hidden tile row stride
#define LDC  68    // f32 pre-LN stride (overlays hidden buffer)

// ---------------------------------------------------------------------------
// Edge update, pipelined with __syncthreads ONLY: 4 tiles x 64 edges/block,
// 256 threads, (256,3) -> VGPR cap 170 (R7's spill was the 85-cap). Tile
// t+1's gather+residual loads are issued BEFORE GEMM1(t); GEMM1's compute
// covers the HBM latency and the post-GEMM1 __syncthreads drains them for
// free. Separate A1/B2 buffers (45KB -> 3 blk/CU). CSR build fused into the
// index-load phase (kills the build_csr dispatch + its 12.8MB re-read).
// ---------------------------------------------------------------------------
__global__ __launch_bounds__(256, 3) void edge_kernel(
    const float* __restrict__ x, const float* __restrict__ ea,
    const void* __restrict__ eidx_raw, const int* __restrict__ flag64,
    const u16* __restrict__ W1p, const float* __restrict__ eb1,
    const u16* __restrict__ W2p, const float* __restrict__ eb2,
    const float* __restrict__ eg, const float* __restrict__ ebt,
    float* __restrict__ out_e, int* __restrict__ cnt, int* __restrict__ idx)
{
    __shared__ __align__(16) u16 A1[64 * LDA1];   // 25.6KB input tile
    __shared__ __align__(16) u16 B2[64 * LDH];    // 17.4KB Hs bf16 / C2 f32
    __shared__ int s_src[T_TILES][64];
    __shared__ int s_dst[T_TILES][64];
    u16* Hs   = B2;
    float* C2 = (float*)B2;

    const int tid = threadIdx.x;
    const int lane = tid & 63;
    const int w = tid >> 6;          // wave 0..3, owns GEMM1 cols 32w..32w+31
    const int l15 = lane & 15;
    const int l4 = lane >> 4;
    const long base = (long)blockIdx.x * (64 * T_TILES);
    const int f64 = *flag64;
    const int lrow = tid >> 2;       // LN/residual row 0..63
    const int lq = tid & 3;
    const int sgs = tid & 15;        // stage: f32x4 index within row
    const int scb = tid >> 4;        // stage: chunk base 0..15

    // ---- residual tile0: issued first (no deps) ----
    const float* rp0 = ea + (base + lrow) * 64 + lq * 16;
    f32x4 rva = *(const f32x4*)(rp0);
    f32x4 rvb = *(const f32x4*)(rp0 + 4);
    f32x4 rvc = *(const f32x4*)(rp0 + 8);
    f32x4 rvd = *(const f32x4*)(rp0 + 12);

    // ---- indices for all 4 tiles; CSR build fused (1 edge per thread) ----
    {
        const int tt = tid >> 6;
        const int r = tid & 63;
        const long ep = base + (long)tt * 64 + r;
        int vs, vd;
        if (f64) {
            vs = (int)((const long long*)eidx_raw)[ep];
            vd = (int)((const long long*)eidx_raw)[N_EDGES + ep];
        } else {
            vs = ((const int*)eidx_raw)[ep];
            vd = ((const int*)eidx_raw)[N_EDGES + ep];
        }
        vs = min(max(vs, 0), N_NODES - 1);
        vd = min(max(vd, 0), N_NODES - 1);
        s_src[tt][r] = vs;
        s_dst[tt][r] = vd;
        int slot = atomicAdd(&cnt[vd], 1);
        if (slot < CAP) idx[(long)vd * CAP + slot] = (int)ep;
    }
    __syncthreads();

    // ---- stage tile0 (immediate, R9-style) ----
    #pragma unroll
    for (int p = 0; p < 8; ++p) {
        int chunk = p * 16 + scb;
        int i = chunk >> 1;
        int seg = chunk & 1;
        const float* srcp = x + (long)(seg ? s_dst[0][i] : s_src[0][i]) * 64;
        f32x4 v = *(const f32x4*)(srcp + sgs * 4);
        u32x2 wv;
        wv[0] = pkbf(v[0], v[1]); wv[1] = pkbf(v[2], v[3]);
        *(u32x2*)&A1[i * LDA1 + seg * 64 + sgs * 4] = wv;
    }
    unsigned prs[8], prsN[8];
    prs[0] = pkbf(rva[0], rva[1]); prs[1] = pkbf(rva[2], rva[3]);
    prs[2] = pkbf(rvb[0], rvb[1]); prs[3] = pkbf(rvb[2], rvb[3]);
    prs[4] = pkbf(rvc[0], rvc[1]); prs[5] = pkbf(rvc[2], rvc[3]);
    prs[6] = pkbf(rvd[0], rvd[1]); prs[7] = pkbf(rvd[2], rvd[3]);
    {
        u16* ap = &A1[lrow * LDA1 + 128 + lq * 16];
        u32x4 w0 = {prs[0], prs[1], prs[2], prs[3]};
        u32x4 w1 = {prs[4], prs[5], prs[6], prs[7]};
        *(u32x4*)(ap) = w0;
        *(u32x4*)(ap + 8) = w1;
    }
    __syncthreads();   // A1 (tile0) ready

    f32x4 gx[8];                  // prefetched next-tile gather (raw f32)
    f32x4 rn0, rn1, rn2, rn3;     // prefetched next-tile residual

    for (int t = 0; t < T_TILES; ++t) {
        const long e0 = base + (long)t * 64;

        // ---- issue tile t+1 loads BEFORE GEMM1: latency hides under MFMA ----
        if (t + 1 < T_TILES) {
            #pragma unroll
            for (int p = 0; p < 8; ++p) {
                int chunk = p * 16 + scb;
                int i = chunk >> 1;
                int seg = chunk & 1;
                gx[p] = *(const f32x4*)(x + (long)(seg ? s_dst[t + 1][i]
                                                      : s_src[t + 1][i]) * 64 + sgs * 4);
            }
            const float* rpN = ea + (base + (long)(t + 1) * 64 + lrow) * 64 + lq * 16;
            rn0 = *(const f32x4*)(rpN);
            rn1 = *(const f32x4*)(rpN + 4);
            rn2 = *(const f32x4*)(rpN + 8);
            rn3 = *(const f32x4*)(rpN + 12);
        }

        // ---- GEMM1: [64x192] @ [192x128], wave w owns cols 32w..32w+31 ----
        s16x8 bf1[6][2];
        #pragma unroll
        for (int ks = 0; ks < 6; ++ks)
            #pragma unroll
            for (int nt = 0; nt < 2; ++nt) {
                int n = 32 * w + nt * 16 + l15;
                bf1[ks][nt] = *(const s16x8*)(W1p + ((size_t)(ks * 128 + n) * 4 + l4) * 8);
            }
        f32x4 acc[4][2] = {};
        #pragma unroll
        for (int ks = 0; ks < 6; ++ks) {
            #pragma unroll
            for (int mt = 0; mt < 4; ++mt) {
                s16x8 a = *(const s16x8*)&A1[(mt * 16 + l15) * LDA1 + ks * 32 + l4 * 8];
                #pragma unroll
                for (int nt = 0; nt < 2; ++nt)
                    acc[mt][nt] = mfma16(a, bf1[ks][nt], acc[mt][nt]);
            }
        }
        __syncthreads();   // all A1 reads done (drains prefetch too — free)

        // ---- bias + relu -> Hs ----
        #pragma unroll
        for (int nt = 0; nt < 2; ++nt) {
            int n = 32 * w + nt * 16 + l15;
            float b = eb1[n];
            #pragma unroll
            for (int mt = 0; mt < 4; ++mt) {
                float v0 = fmaxf(acc[mt][nt][0] + b, 0.f);
                float v1 = fmaxf(acc[mt][nt][1] + b, 0.f);
                float v2 = fmaxf(acc[mt][nt][2] + b, 0.f);
                float v3 = fmaxf(acc[mt][nt][3] + b, 0.f);
                unsigned w0 = pkbf(v0, v1), w1 = pkbf(v2, v3);
                int r0 = mt * 16 + l4 * 4;
                Hs[(r0 + 0) * LDH + n] = (u16)w0;
                Hs[(r0 + 1) * LDH + n] = (u16)(w0 >> 16);
                Hs[(r0 + 2) * LDH + n] = (u16)w1;
                Hs[(r0 + 3) * LDH + n] = (u16)(w1 >> 16);
            }
        }

        // ---- convert prefetched tile t+1 into A1 (A1 dead after GEMM1) ----
        if (t + 1 < T_TILES) {
            #pragma unroll
            for (int p = 0; p < 8; ++p) {
                int chunk = p * 16 + scb;
                int i = chunk >> 1;
                int seg = chunk & 1;
                u32x2 wv;
                wv[0] = pkbf(gx[p][0], gx[p][1]); wv[1] = pkbf(gx[p][2], gx[p][3]);
                *(u32x2*)&A1[i * LDA1 + seg * 64 + sgs * 4] = wv;
            }
            prsN[0] = pkbf(rn0[0], rn0[1]); prsN[1] = pkbf(rn0[2], rn0[3]);
            prsN[2] = pkbf(rn1[0], rn1[1]); prsN[3] = pkbf(rn1[2], rn1[3]);
            prsN[4] = pkbf(rn2[0], rn2[1]); prsN[5] = pkbf(rn2[2], rn2[3]);
            prsN[6] = pkbf(rn3[0], rn3[1]); prsN[7] = pkbf(rn3[2], rn3[3]);
            u16* ap = &A1[lrow * LDA1 + 128 + lq * 16];
            u32x4 w0 = {prsN[0], prsN[1], prsN[2], prsN[3]};
            u32x4 w1 = {prsN[4], prsN[5], prsN[6], prsN[7]};
            *(u32x4*)(ap) = w0;
            *(u32x4*)(ap + 8) = w1;
        }
        __syncthreads();   // Hs visible (A1(t+1) writes also ordered)

        // ---- GEMM2: [64x128] @ [128x64], wave w owns cols 16w..16w+15 ----
        s16x8 bf2v[4];
        #pragma unroll
        for (int ks = 0; ks < 4; ++ks)
            bf2v[ks] = *(const s16x8*)(W2p + ((size_t)(ks * 64 + 16 * w + l15) * 4 + l4) * 8);
        f32x4 acc2[4] = {};
        #pragma unroll
        for (int ks = 0; ks < 4; ++ks) {
            #pragma unroll
            for (int mt = 0; mt < 4; ++mt) {
                s16x8 a = *(const s16x8*)&Hs[(mt * 16 + l15) * LDH + ks * 32 + l4 * 8];
                acc2[mt] = mfma16(a, bf2v[ks], acc2[mt]);
            }
        }
        __syncthreads();   // Hs reads done; C2 overlay writable

        {
            int n = 16 * w + l15;
            float b = eb2[n];
            #pragma unroll
            for (int mt = 0; mt < 4; ++mt)
                #pragma unroll
                for (int r = 0; r < 4; ++r)
                    C2[(mt * 16 + l4 * 4 + r) * LDC + n] = acc2[mt][r] + b;
        }
        __syncthreads();   // C2 visible

        // ---- LayerNorm + residual(prs regs) + store ----
        {
            const float* cp = &C2[lrow * LDC + lq * 16];
            float vv[16];
            #pragma unroll
            for (int i = 0; i < 4; ++i) {
                f32x4 tv = *(const f32x4*)(cp + i * 4);
                vv[i * 4 + 0] = tv[0]; vv[i * 4 + 1] = tv[1];
                vv[i * 4 + 2] = tv[2]; vv[i * 4 + 3] = tv[3];
            }
            float s = 0.f, ss = 0.f;
            #pragma unroll
            for (int i = 0; i < 16; ++i) { s += vv[i]; ss += vv[i] * vv[i]; }
            s  += __shfl_xor(s, 1);  s  += __shfl_xor(s, 2);
            ss += __shfl_xor(ss, 1); ss += __shfl_xor(ss, 2);
            const float mu = s * (1.0f / 64.0f);
            const float var = ss * (1.0f / 64.0f) - mu * mu;
            const float rs = rsqrtf(var + 1e-5f);
            float* op = out_e + (e0 + lrow) * 64 + lq * 16;
            #pragma unroll
            for (int i4 = 0; i4 < 4; ++i4) {
                f32x4 o;
                #pragma unroll
                for (int j2 = 0; j2 < 2; ++j2) {
                    union { unsigned u; float f; } lo, hi;
                    lo.u = prs[i4 * 2 + j2] << 16;
                    hi.u = prs[i4 * 2 + j2] & 0xffff0000u;
                    const int c0 = lq * 16 + i4 * 4 + j2 * 2;
                    o[j2 * 2 + 0] = (vv[i4 * 4 + j2 * 2 + 0] - mu) * rs * eg[c0] + ebt[c0] + lo.f;
                    o[j2 * 2 + 1] = (vv[i4 * 4 + j2 * 2 + 1] - mu) * rs * eg[c0 + 1] + ebt[c0 + 1] + hi.f;
                }
                *(f32x4*)(op + i4 * 4) = o;
            }
        }
        #pragma unroll
        for (int i = 0; i < 8; ++i) prs[i] = prsN[i];
        // no extra sync: next iteration's post-GEMM1 __syncthreads orders
        // this LN's C2 reads against the next Hs/B2 writes, and this tile's
        // A1(t+1) writes against next GEMM1's A1 reads.
    }
}

// ---------------------------------------------------------------------------
// Node update: 64 nodes/block, 256 threads, single LDS buffer (Hs/C2 overlay
// A) -> 17.4KB -> 6 blocks/CU. CSR gather from out_e (plain loads; NT
// regressed in R8). Unchanged from R9.
// ---------------------------------------------------------------------------
__global__ __launch_bounds__(256, 6) void node_kernel(
    const float* __restrict__ x, const float* __restrict__ out_e,
    const int* __restrict__ cnt, const int* __restrict__ idx,
    const u16* __restrict__ W1p, const float* __restrict__ nb1,
    const u16* __restrict__ W2p, const float* __restrict__ nb2,
    const float* __restrict__ ng, const float* __restrict__ nbt,
    float* __restrict__ out_x)
{
    __shared__ __align__(16) u16 A[64 * LDH];    // Hs and C2 overlay
    u16* Hs   = A;
    float* C2 = (float*)A;

    const int tid = threadIdx.x;
    const int lane = tid & 63;
    const int w = tid >> 6;
    const int l15 = lane & 15;
    const int l4 = lane >> 4;
    const int n0 = blockIdx.x * 64;

    const int lrow = tid >> 2;
    const int lq = tid & 3;
    {
        int n = n0 + lrow;
        if (n >= N_NODES) n = N_NODES - 1;
        int c = cnt[n];
        if (c > CAP) c = CAP;
        const int* ip = idx + (long)n * CAP;
        f32x4 s0 = {}, s1 = {}, s2 = {}, s3 = {};
        int j = 0;
        for (; j + 4 <= c; j += 4) {
            int ev0 = ip[j], ev1 = ip[j + 1], ev2 = ip[j + 2], ev3 = ip[j + 3];
            const float* p0 = out_e + (long)ev0 * 64 + lq * 16;
            const float* p1 = out_e + (long)ev1 * 64 + lq * 16;
            const float* p2 = out_e + (long)ev2 * 64 + lq * 16;
            const float* p3 = out_e + (long)ev3 * 64 + lq * 16;
            f32x4 a00 = *(const f32x4*)(p0);     f32x4 a01 = *(const f32x4*)(p0 + 4);
            f32x4 a02 = *(const f32x4*)(p0 + 8); f32x4 a03 = *(const f32x4*)(p0 + 12);
            f32x4 a10 = *(const f32x4*)(p1);     f32x4 a11 = *(const f32x4*)(p1 + 4);
            f32x4 a12 = *(const f32x4*)(p1 + 8); f32x4 a13 = *(const f32x4*)(p1 + 12);
            f32x4 a20 = *(const f32x4*)(p2);     f32x4 a21 = *(const f32x4*)(p2 + 4);
            f32x4 a22 = *(const f32x4*)(p2 + 8); f32x4 a23 = *(const f32x4*)(p2 + 12);
            f32x4 a30 = *(const f32x4*)(p3);     f32x4 a31 = *(const f32x4*)(p3 + 4);
            f32x4 a32 = *(const f32x4*)(p3 + 8); f32x4 a33 = *(const f32x4*)(p3 + 12);
            s0 += a00 + a10 + a20 + a30;
            s1 += a01 + a11 + a21 + a31;
            s2 += a02 + a12 + a22 + a32;
            s3 += a03 + a13 + a23 + a33;
        }
        for (; j < c; ++j) {
            int ev = ip[j];
            const float* p = out_e + (long)ev * 64 + lq * 16;
            s0 += *(const f32x4*)(p);
            s1 += *(const f32x4*)(p + 4);
            s2 += *(const f32x4*)(p + 8);
            s3 += *(const f32x4*)(p + 12);
        }
        u16* ap = &A[lrow * LDH + 64 + lq * 16];
        u32x2 o;
        o[0] = pkbf(s0[0], s0[1]); o[1] = pkbf(s0[2], s0[3]);
        *(u32x2*)(ap) = o;
        o[0] = pkbf(s1[0], s1[1]); o[1] = pkbf(s1[2], s1[3]);
        *(u32x2*)(ap + 4) = o;
        o[0] = pkbf(s2[0], s2[1]); o[1] = pkbf(s2[2], s2[3]);
        *(u32x2*)(ap + 8) = o;
        o[0] = pkbf(s3[0], s3[1]); o[1] = pkbf(s3[2], s3[3]);
        *(u32x2*)(ap + 12) = o;
    }

    {
        const int s = tid & 15;
        const int rb = tid >> 4;
        #pragma unroll
        for (int p = 0; p < 4; ++p) {
            int row = p * 16 + rb;
            long gr = n0 + row;
            if (gr >= N_NODES) gr = N_NODES - 1;
            f32x4 v = *(const f32x4*)(x + gr * 64 + s * 4);
            u32x2 o;
            o[0] = pkbf(v[0], v[1]); o[1] = pkbf(v[2], v[3]);
            *(u32x2*)&A[row * LDH + s * 4] = o;
        }
    }
    __syncthreads();

    s16x8 bf1[4][2];
    #pragma unroll
    for (int ks = 0; ks < 4; ++ks)
        #pragma unroll
        for (int nt = 0; nt < 2; ++nt) {
            int n = 32 * w + nt * 16 + l15;
            bf1[ks][nt] = *(const s16x8*)(W1p + ((size_t)(ks * 128 + n) * 4 + l4) * 8);
        }
    f32x4 acc[4][2] = {};
    #pragma unroll
    for (int ks = 0; ks < 4; ++ks) {
        #pragma unroll
        for (int mt = 0; mt < 4; ++mt) {
            s16x8 a = *(const s16x8*)&A[(mt * 16 + l15) * LDH + ks * 32 + l4 * 8];
            #pragma unroll
            for (int nt = 0; nt < 2; ++nt)
                acc[mt][nt] = mfma16(a, bf1[ks][nt], acc[mt][nt]);
        }
    }
    __syncthreads();

    #pragma unroll
    for (int nt = 0; nt < 2; ++nt) {
        int n = 32 * w + nt * 16 + l15;
        float b = nb1[n];
        #pragma unroll
        for (int mt = 0; mt < 4; ++mt) {
            float v0 = fmaxf(acc[mt][nt][0] + b, 0.f);
            float v1 = fmaxf(acc[mt][nt][1] + b, 0.f);
            float v2 = fmaxf(acc[mt][nt][2] + b, 0.f);
            float v3 = fmaxf(acc[mt][nt][3] + b, 0.f);
            unsigned w0 = pkbf(v0, v1), w1 = pkbf(v2, v3);
            int r0 = mt * 16 + l4 * 4;
            Hs[(r0 + 0) * LDH + n] = (u16)w0;
            Hs[(r0 + 1) * LDH + n] = (u16)(w0 >> 16);
            Hs[(r0 + 2) * LDH + n] = (u16)w1;
            Hs[(r0 + 3) * LDH + n] = (u16)(w1 >> 16);
        }
    }
    __syncthreads();

    s16x8 bf2v[4];
    #pragma unroll
    for (int ks = 0; ks < 4; ++ks)
        bf2v[ks] = *(const s16x8*)(W2p + ((size_t)(ks * 64 + 16 * w + l15) * 4 + l4) * 8);
    f32x4 acc2[4] = {};
    #pragma unroll
    for (int ks = 0; ks < 4; ++ks) {
        #pragma unroll
        for (int mt = 0; mt < 4; ++mt) {
            s16x8 a = *(const s16x8*)&Hs[(mt * 16 + l15) * LDH + ks * 32 + l4 * 8];
            acc2[mt] = mfma16(a, bf2v[ks], acc2[mt]);
        }
    }
    __syncthreads();

    {
        int n = 16 * w + l15;
        float b = nb2[n];
        #pragma unroll
        for (int mt = 0; mt < 4; ++mt)
            #pragma unroll
            for (int r = 0; r < 4; ++r)
                C2[(mt * 16 + l4 * 4 + r) * LDC + n] = acc2[mt][r] + b;
    }
    __syncthreads();

    {
        const float* cp = &C2[lrow * LDC + lq * 16];
        float vv[16];
        #pragma unroll
        for (int i = 0; i < 4; ++i) {
            f32x4 t = *(const f32x4*)(cp + i * 4);
            vv[i * 4 + 0] = t[0]; vv[i * 4 + 1] = t[1];
            vv[i * 4 + 2] = t[2]; vv[i * 4 + 3] = t[3];
        }
        float s = 0.f, ss = 0.f;
        #pragma unroll
        for (int i = 0; i < 16; ++i) { s += vv[i]; ss += vv[i] * vv[i]; }
        s  += __shfl_xor(s, 1);  s  += __shfl_xor(s, 2);
        ss += __shfl_xor(ss, 1); ss += __shfl_xor(ss, 2);
        const float mu = s * (1.0f / 64.0f);
        const float var = ss * (1.0f / 64.0f) - mu * mu;
        const float rs = rsqrtf(var + 1e-5f);
        const long gnode = n0 + lrow;
        if (gnode < N_NODES) {
            const float* rp = x + gnode * 64 + lq * 16;
            float* op = out_x + gnode * 64 + lq * 16;
            #pragma unroll
            for (int i4 = 0; i4 < 4; ++i4) {
                f32x4 res = *(const f32x4*)(rp + i4 * 4);
                f32x4 o;
                #pragma unroll
                for (int j = 0; j < 4; ++j) {
                    const int c = lq * 16 + i4 * 4 + j;
                    o[j] = (vv[i4 * 4 + j] - mu) * rs * ng[c] + nbt[c] + res[j];
                }
                *(f32x4*)(op + i4 * 4) = o;
            }
        }
    }
}

extern "C" void kernel_launch(void* const* d_in, const int* in_sizes, int n_in,
                              void* d_out, int out_size, void* d_ws, size_t ws_size,
                              hipStream_t stream) {
    const float* x   = (const float*)d_in[0];
    const float* ea  = (const float*)d_in[1];
    const void*  ei  = d_in[2];
    const float* eW1 = (const float*)d_in[3];
    const float* eb1 = (const float*)d_in[4];
    const float* eW2 = (const float*)d_in[5];
    const float* eb2 = (const float*)d_in[6];
    const float* eg  = (const float*)d_in[7];
    const float* ebt = (const float*)d_in[8];
    const float* nW1 = (const float*)d_in[9];
    const float* nb1 = (const float*)d_in[10];
    const float* nW2 = (const float*)d_in[11];
    const float* nb2 = (const float*)d_in[12];
    const float* ng  = (const float*)d_in[13];
    const float* nbt = (const float*)d_in[14];

    float* out   = (float*)d_out;
    float* out_x = out;                            // [100000, 64]
    float* out_e = out + (size_t)N_NODES * 64;     // [1600000, 64]

    // ws layout: packed weights 114688 B | flag 4 B | pad |
    //            cnt 400000 B | pad | idx 100000*CAP*4 B   (~24.5 MB total)
    u16* W1p   = (u16*)d_ws;
    u16* W2p   = W1p + 24576;
    u16* nW1p  = W2p + 8192;
    u16* nW2p  = nW1p + 16384;
    int* flag  = (int*)((char*)d_ws + 114688);
    int* cnt   = (int*)((char*)d_ws + 114944);
    int* idx   = (int*)((char*)d_ws + 515072);

    hipMemsetAsync(cnt, 0, (size_t)N_NODES * sizeof(int), stream);
    pack_w<<<225, 256, 0, stream>>>(eW1, eW2, nW1, nW2, W1p, W2p, nW1p, nW2p,
                                    (const int*)ei, flag);
    edge_kernel<<<N_EDGES / (64 * T_TILES), 256, 0, stream>>>(
        x, ea, ei, flag, W1p, eb1, W2p, eb2, eg, ebt, out_e, cnt, idx);
    node_kernel<<<(N_NODES + 63) / 64, 256, 0, stream>>>(x, out_e, cnt, idx,
                                                         nW1p, nb1, nW2p, nb2,
                                                         ng, nbt, out_x);
}

// Round 13
// 860.951 us; speedup vs baseline: 1.0602x; 1.0000x over previous
//
#include <hip/hip_runtime.h>

#define N_NODES 100000
#define N_EDGES 1600000
#define CAP 60            // per-node edge-list capacity; P(deg>60) ~ 1e-10
#define T_TILES 4         // edge tiles (64 edges each) per block

typedef unsigned short u16;
typedef short s16x8 __attribute__((ext_vector_type(8)));
typedef float f32x4 __attribute__((ext_vector_type(4)));
typedef unsigned u32x2 __attribute__((ext_vector_type(2)));
typedef unsigned u32x4 __attribute__((ext_vector_type(4)));

__device__ __forceinline__ u16 f2bf(float f) {   // software RNE, proven R2-R12
    union { float f; unsigned int i; } c;
    c.f = f;
    unsigned int u = c.i;
    return (u16)((u + 0x7fffu + ((u >> 16) & 1u)) >> 16);
}

// packed f32x2 -> bf16x2 (software RNE). History: hand-written
// v_cvt_pk_bf16_f32 asm corrupted values (R5); NT loads regressed (R8);
// raw s_barrier pipeline raced (R11); holding 48-reg bf1 + prefetch spilled
// (R12 — load B-fragments per-ks when prefetch regs are live).
__device__ __forceinline__ unsigned pkbf(float lo, float hi) {
    return (unsigned)f2bf(lo) | ((unsigned)f2bf(hi) << 16);
}

__device__ __forceinline__ f32x4 mfma16(s16x8 a, s16x8 b, f32x4 c) {
    return __builtin_amdgcn_mfma_f32_16x16x32_bf16(a, b, c, 0, 0, 0);
}

// ---------------------------------------------------------------------------
// Weight repack (f32 -> bf16) into MFMA B-fragment order; block 224 instead
// runs the edge_index width detection (int64 => odd int32 words all zero).
// ---------------------------------------------------------------------------
__global__ __launch_bounds__(256) void pack_w(
    const float* __restrict__ eW1, const float* __restrict__ eW2,
    const float* __restrict__ nW1, const float* __restrict__ nW2,
    u16* __restrict__ W1p, u16* __restrict__ W2p,
    u16* __restrict__ nW1p, u16* __restrict__ nW2p,
    const int* __restrict__ eidx, int* __restrict__ flag)
{
    if (blockIdx.x == 224) {                       // fused detect_idx
        __shared__ int snz;
        const int tid = threadIdx.x;
        if (tid == 0) snz = 0;
        __syncthreads();
        int nz = 0;
        #pragma unroll
        for (int k = 0; k < 8; ++k) {
            long pos = 1 + 2 * ((long)tid * 781 + k * 97);
            if (pos < 2L * N_EDGES) nz |= (eidx[pos] != 0);
        }
        if (nz) snz = 1;
        __syncthreads();
        if (tid == 0) *flag = snz ? 0 : 1;
        return;
    }
    int t = blockIdx.x * 256 + threadIdx.x;
    if (t < 24576) {                               // eW1 [192][128]
        int j = t & 7, kg = (t >> 3) & 3, n = (t >> 5) & 127, ks = t >> 12;
        W1p[t] = f2bf(eW1[(ks * 32 + kg * 8 + j) * 128 + n]);
    } else if (t < 24576 + 8192) {                 // eW2 [128][64]
        int u = t - 24576;
        int j = u & 7, kg = (u >> 3) & 3, n = (u >> 5) & 63, ks = u >> 11;
        W2p[u] = f2bf(eW2[(ks * 32 + kg * 8 + j) * 64 + n]);
    } else if (t < 24576 + 8192 + 16384) {         // nW1 [128][128]
        int u = t - (24576 + 8192);
        int j = u & 7, kg = (u >> 3) & 3, n = (u >> 5) & 127, ks = u >> 12;
        nW1p[u] = f2bf(nW1[(ks * 32 + kg * 8 + j) * 128 + n]);
    } else if (t < 24576 + 8192 + 16384 + 8192) {  // nW2 [128][64]
        int u = t - (24576 + 8192 + 16384);
        int j = u & 7, kg = (u >> 3) & 3, n = (u >> 5) & 63, ks = u >> 11;
        nW2p[u] = f2bf(nW2[(ks * 32 + kg * 8 + j) * 64 + n]);
    }
}

#define LDA1 200   // 64x192 bf16 input tile row stride (400B = 4-bank step)
#define LDH  136   // hidden tile row stride
#define LDC  68    // f32 pre-LN stride (overlays hidden buffer)

// ---------------------------------------------------------------------------
// Edge update, pipelined with __syncthreads ONLY (R12 schedule, correctness-
// proven) with per-ks B-fragment loads so the GEMM1-time live set is ~122
// regs (< 170 cap) instead of R12's ~156 (which spilled). 4 tiles x 64
// edges/block; tile t+1's gather+residual issued BEFORE GEMM1(t), drained by
// the post-GEMM1 __syncthreads for free, converted into A1 after. CSR build
// fused into the index-load phase.
// ---------------------------------------------------------------------------
__global__ __launch_bounds__(256, 3) void edge_kernel(
    const float* __restrict__ x, const float* __restrict__ ea,
    const void* __restrict__ eidx_raw, const int* __restrict__ flag64,
    const u16* __restrict__ W1p, const float* __restrict__ eb1,
    const u16* __restrict__ W2p, const float* __restrict__ eb2,
    const float* __restrict__ eg, const float* __restrict__ ebt,
    float* __restrict__ out_e, int* __restrict__ cnt, int* __restrict__ idx)
{
    __shared__ __align__(16) u16 A1[64 * LDA1];   // 25.6KB input tile
    __shared__ __align__(16) u16 B2[64 * LDH];    // 17.4KB Hs bf16 / C2 f32
    __shared__ int s_src[T_TILES][64];
    __shared__ int s_dst[T_TILES][64];
    u16* Hs   = B2;
    float* C2 = (float*)B2;

    const int tid = threadIdx.x;
    const int lane = tid & 63;
    const int w = tid >> 6;          // wave 0..3, owns GEMM1 cols 32w..32w+31
    const int l15 = lane & 15;
    const int l4 = lane >> 4;
    const long base = (long)blockIdx.x * (64 * T_TILES);
    const int f64 = *flag64;
    const int lrow = tid >> 2;       // LN/residual row 0..63
    const int lq = tid & 3;
    const int sgs = tid & 15;        // stage: f32x4 index within row
    const int scb = tid >> 4;        // stage: chunk base 0..15

    // ---- residual tile0: issued first (no deps) ----
    const float* rp0 = ea + (base + lrow) * 64 + lq * 16;
    f32x4 rva = *(const f32x4*)(rp0);
    f32x4 rvb = *(const f32x4*)(rp0 + 4);
    f32x4 rvc = *(const f32x4*)(rp0 + 8);
    f32x4 rvd = *(const f32x4*)(rp0 + 12);

    // ---- indices for all 4 tiles; CSR build fused (1 edge per thread) ----
    {
        const int tt = tid >> 6;
        const int r = tid & 63;
        const long ep = base + (long)tt * 64 + r;
        int vs, vd;
        if (f64) {
            vs = (int)((const long long*)eidx_raw)[ep];
            vd = (int)((const long long*)eidx_raw)[N_EDGES + ep];
        } else {
            vs = ((const int*)eidx_raw)[ep];
            vd = ((const int*)eidx_raw)[N_EDGES + ep];
        }
        vs = min(max(vs, 0), N_NODES - 1);
        vd = min(max(vd, 0), N_NODES - 1);
        s_src[tt][r] = vs;
        s_dst[tt][r] = vd;
        int slot = atomicAdd(&cnt[vd], 1);
        if (slot < CAP) idx[(long)vd * CAP + slot] = (int)ep;
    }
    __syncthreads();

    // ---- stage tile0 (immediate, R9-style) ----
    #pragma unroll
    for (int p = 0; p < 8; ++p) {
        int chunk = p * 16 + scb;
        int i = chunk >> 1;
        int seg = chunk & 1;
        const float* srcp = x + (long)(seg ? s_dst[0][i] : s_src[0][i]) * 64;
        f32x4 v = *(const f32x4*)(srcp + sgs * 4);
        u32x2 wv;
        wv[0] = pkbf(v[0], v[1]); wv[1] = pkbf(v[2], v[3]);
        *(u32x2*)&A1[i * LDA1 + seg * 64 + sgs * 4] = wv;
    }
    unsigned prs[8], prsN[8];
    prs[0] = pkbf(rva[0], rva[1]); prs[1] = pkbf(rva[2], rva[3]);
    prs[2] = pkbf(rvb[0], rvb[1]); prs[3] = pkbf(rvb[2], rvb[3]);
    prs[4] = pkbf(rvc[0], rvc[1]); prs[5] = pkbf(rvc[2], rvc[3]);
    prs[6] = pkbf(rvd[0], rvd[1]); prs[7] = pkbf(rvd[2], rvd[3]);
    {
        u16* ap = &A1[lrow * LDA1 + 128 + lq * 16];
        u32x4 w0 = {prs[0], prs[1], prs[2], prs[3]};
        u32x4 w1 = {prs[4], prs[5], prs[6], prs[7]};
        *(u32x4*)(ap) = w0;
        *(u32x4*)(ap + 8) = w1;
    }
    __syncthreads();   // A1 (tile0) ready

    f32x4 gx[8];                  // prefetched next-tile gather (raw f32)
    f32x4 rn0, rn1, rn2, rn3;     // prefetched next-tile residual

    for (int t = 0; t < T_TILES; ++t) {
        const long e0 = base + (long)t * 64;

        // ---- issue tile t+1 loads BEFORE GEMM1: latency hides under MFMA ----
        if (t + 1 < T_TILES) {
            #pragma unroll
            for (int p = 0; p < 8; ++p) {
                int chunk = p * 16 + scb;
                int i = chunk >> 1;
                int seg = chunk & 1;
                gx[p] = *(const f32x4*)(x + (long)(seg ? s_dst[t + 1][i]
                                                      : s_src[t + 1][i]) * 64 + sgs * 4);
            }
            const float* rpN = ea + (base + (long)(t + 1) * 64 + lrow) * 64 + lq * 16;
            rn0 = *(const f32x4*)(rpN);
            rn1 = *(const f32x4*)(rpN + 4);
            rn2 = *(const f32x4*)(rpN + 8);
            rn3 = *(const f32x4*)(rpN + 12);
        }

        // ---- GEMM1: [64x192] @ [192x128]; B-fragments loaded PER-KS so the
        //      live set stays ~122 regs with the prefetch in flight (R12) ----
        f32x4 acc[4][2] = {};
        #pragma unroll
        for (int ks = 0; ks < 6; ++ks) {
            s16x8 b0 = *(const s16x8*)(W1p + ((size_t)(ks * 128 + 32 * w + l15) * 4 + l4) * 8);
            s16x8 b1 = *(const s16x8*)(W1p + ((size_t)(ks * 128 + 32 * w + 16 + l15) * 4 + l4) * 8);
            #pragma unroll
            for (int mt = 0; mt < 4; ++mt) {
                s16x8 a = *(const s16x8*)&A1[(mt * 16 + l15) * LDA1 + ks * 32 + l4 * 8];
                acc[mt][0] = mfma16(a, b0, acc[mt][0]);
                acc[mt][1] = mfma16(a, b1, acc[mt][1]);
            }
        }
        __syncthreads();   // all A1 reads done (drains prefetch too — free)

        // ---- bias + relu -> Hs ----
        #pragma unroll
        for (int nt = 0; nt < 2; ++nt) {
            int n = 32 * w + nt * 16 + l15;
            float b = eb1[n];
            #pragma unroll
            for (int mt = 0; mt < 4; ++mt) {
                float v0 = fmaxf(acc[mt][nt][0] + b, 0.f);
                float v1 = fmaxf(acc[mt][nt][1] + b, 0.f);
                float v2 = fmaxf(acc[mt][nt][2] + b, 0.f);
                float v3 = fmaxf(acc[mt][nt][3] + b, 0.f);
                unsigned w0 = pkbf(v0, v1), w1 = pkbf(v2, v3);
                int r0 = mt * 16 + l4 * 4;
                Hs[(r0 + 0) * LDH + n] = (u16)w0;
                Hs[(r0 + 1) * LDH + n] = (u16)(w0 >> 16);
                Hs[(r0 + 2) * LDH + n] = (u16)w1;
                Hs[(r0 + 3) * LDH + n] = (u16)(w1 >> 16);
            }
        }

        // ---- convert prefetched tile t+1 into A1 (A1 dead after GEMM1) ----
        if (t + 1 < T_TILES) {
            #pragma unroll
            for (int p = 0; p < 8; ++p) {
                int chunk = p * 16 + scb;
                int i = chunk >> 1;
                int seg = chunk & 1;
                u32x2 wv;
                wv[0] = pkbf(gx[p][0], gx[p][1]); wv[1] = pkbf(gx[p][2], gx[p][3]);
                *(u32x2*)&A1[i * LDA1 + seg * 64 + sgs * 4] = wv;
            }
            prsN[0] = pkbf(rn0[0], rn0[1]); prsN[1] = pkbf(rn0[2], rn0[3]);
            prsN[2] = pkbf(rn1[0], rn1[1]); prsN[3] = pkbf(rn1[2], rn1[3]);
            prsN[4] = pkbf(rn2[0], rn2[1]); prsN[5] = pkbf(rn2[2], rn2[3]);
            prsN[6] = pkbf(rn3[0], rn3[1]); prsN[7] = pkbf(rn3[2], rn3[3]);
            u16* ap = &A1[lrow * LDA1 + 128 + lq * 16];
            u32x4 w0 = {prsN[0], prsN[1], prsN[2], prsN[3]};
            u32x4 w1 = {prsN[4], prsN[5], prsN[6], prsN[7]};
            *(u32x4*)(ap) = w0;
            *(u32x4*)(ap + 8) = w1;
        }
        __syncthreads();   // Hs visible (A1(t+1) writes also ordered)

        // ---- GEMM2: [64x128] @ [128x64]; B-fragment per-ks ----
        f32x4 acc2[4] = {};
        #pragma unroll
        for (int ks = 0; ks < 4; ++ks) {
            s16x8 b2 = *(const s16x8*)(W2p + ((size_t)(ks * 64 + 16 * w + l15) * 4 + l4) * 8);
            #pragma unroll
            for (int mt = 0; mt < 4; ++mt) {
                s16x8 a = *(const s16x8*)&Hs[(mt * 16 + l15) * LDH + ks * 32 + l4 * 8];
                acc2[mt] = mfma16(a, b2, acc2[mt]);
            }
        }
        __syncthreads();   // Hs reads done; C2 overlay writable

        {
            int n = 16 * w + l15;
            float b = eb2[n];
            #pragma unroll
            for (int mt = 0; mt < 4; ++mt)
                #pragma unroll
                for (int r = 0; r < 4; ++r)
                    C2[(mt * 16 + l4 * 4 + r) * LDC + n] = acc2[mt][r] + b;
        }
        __syncthreads();   // C2 visible

        // ---- LayerNorm + residual(prs regs) + store ----
        {
            const float* cp = &C2[lrow * LDC + lq * 16];
            float vv[16];
            #pragma unroll
            for (int i = 0; i < 4; ++i) {
                f32x4 tv = *(const f32x4*)(cp + i * 4);
                vv[i * 4 + 0] = tv[0]; vv[i * 4 + 1] = tv[1];
                vv[i * 4 + 2] = tv[2]; vv[i * 4 + 3] = tv[3];
            }
            float s = 0.f, ss = 0.f;
            #pragma unroll
            for (int i = 0; i < 16; ++i) { s += vv[i]; ss += vv[i] * vv[i]; }
            s  += __shfl_xor(s, 1);  s  += __shfl_xor(s, 2);
            ss += __shfl_xor(ss, 1); ss += __shfl_xor(ss, 2);
            const float mu = s * (1.0f / 64.0f);
            const float var = ss * (1.0f / 64.0f) - mu * mu;
            const float rs = rsqrtf(var + 1e-5f);
            float* op = out_e + (e0 + lrow) * 64 + lq * 16;
            #pragma unroll
            for (int i4 = 0; i4 < 4; ++i4) {
                f32x4 o;
                #pragma unroll
                for (int j2 = 0; j2 < 2; ++j2) {
                    union { unsigned u; float f; } lo, hi;
                    lo.u = prs[i4 * 2 + j2] << 16;
                    hi.u = prs[i4 * 2 + j2] & 0xffff0000u;
                    const int c0 = lq * 16 + i4 * 4 + j2 * 2;
                    o[j2 * 2 + 0] = (vv[i4 * 4 + j2 * 2 + 0] - mu) * rs * eg[c0] + ebt[c0] + lo.f;
                    o[j2 * 2 + 1] = (vv[i4 * 4 + j2 * 2 + 1] - mu) * rs * eg[c0 + 1] + ebt[c0 + 1] + hi.f;
                }
                *(f32x4*)(op + i4 * 4) = o;
            }
        }
        #pragma unroll
        for (int i = 0; i < 8; ++i) prs[i] = prsN[i];
        // no extra sync: next iteration's post-GEMM1 __syncthreads orders
        // this LN's C2 reads against the next Hs/B2 writes, and this tile's
        // A1(t+1) writes against next GEMM1's A1 reads.
    }
}

// ---------------------------------------------------------------------------
// Node update: 64 nodes/block, 256 threads, single LDS buffer (Hs/C2 overlay
// A) -> 17.4KB -> 6 blocks/CU. CSR gather from out_e (plain loads; NT
// regressed in R8). Unchanged from R9.
// ---------------------------------------------------------------------------
__global__ __launch_bounds__(256, 6) void node_kernel(
    const float* __restrict__ x, const float* __restrict__ out_e,
    const int* __restrict__ cnt, const int* __restrict__ idx,
    const u16* __restrict__ W1p, const float* __restrict__ nb1,
    const u16* __restrict__ W2p, const float* __restrict__ nb2,
    const float* __restrict__ ng, const float* __restrict__ nbt,
    float* __restrict__ out_x)
{
    __shared__ __align__(16) u16 A[64 * LDH];    // Hs and C2 overlay
    u16* Hs   = A;
    float* C2 = (float*)A;

    const int tid = threadIdx.x;
    const int lane = tid & 63;
    const int w = tid >> 6;
    const int l15 = lane & 15;
    const int l4 = lane >> 4;
    const int n0 = blockIdx.x * 64;

    const int lrow = tid >> 2;
    const int lq = tid & 3;
    {
        int n = n0 + lrow;
        if (n >= N_NODES) n = N_NODES - 1;
        int c = cnt[n];
        if (c > CAP) c = CAP;
        const int* ip = idx + (long)n * CAP;
        f32x4 s0 = {}, s1 = {}, s2 = {}, s3 = {};
        int j = 0;
        for (; j + 4 <= c; j += 4) {
            int ev0 = ip[j], ev1 = ip[j + 1], ev2 = ip[j + 2], ev3 = ip[j + 3];
            const float* p0 = out_e + (long)ev0 * 64 + lq * 16;
            const float* p1 = out_e + (long)ev1 * 64 + lq * 16;
            const float* p2 = out_e + (long)ev2 * 64 + lq * 16;
            const float* p3 = out_e + (long)ev3 * 64 + lq * 16;
            f32x4 a00 = *(const f32x4*)(p0);     f32x4 a01 = *(const f32x4*)(p0 + 4);
            f32x4 a02 = *(const f32x4*)(p0 + 8); f32x4 a03 = *(const f32x4*)(p0 + 12);
            f32x4 a10 = *(const f32x4*)(p1);     f32x4 a11 = *(const f32x4*)(p1 + 4);
            f32x4 a12 = *(const f32x4*)(p1 + 8); f32x4 a13 = *(const f32x4*)(p1 + 12);
            f32x4 a20 = *(const f32x4*)(p2);     f32x4 a21 = *(const f32x4*)(p2 + 4);
            f32x4 a22 = *(const f32x4*)(p2 + 8); f32x4 a23 = *(const f32x4*)(p2 + 12);
            f32x4 a30 = *(const f32x4*)(p3);     f32x4 a31 = *(const f32x4*)(p3 + 4);
            f32x4 a32 = *(const f32x4*)(p3 + 8); f32x4 a33 = *(const f32x4*)(p3 + 12);
            s0 += a00 + a10 + a20 + a30;
            s1 += a01 + a11 + a21 + a31;
            s2 += a02 + a12 + a22 + a32;
            s3 += a03 + a13 + a23 + a33;
        }
        for (; j < c; ++j) {
            int ev = ip[j];
            const float* p = out_e + (long)ev * 64 + lq * 16;
            s0 += *(const f32x4*)(p);
            s1 += *(const f32x4*)(p + 4);
            s2 += *(const f32x4*)(p + 8);
            s3 += *(const f32x4*)(p + 12);
        }
        u16* ap = &A[lrow * LDH + 64 + lq * 16];
        u32x2 o;
        o[0] = pkbf(s0[0], s0[1]); o[1] = pkbf(s0[2], s0[3]);
        *(u32x2*)(ap) = o;
        o[0] = pkbf(s1[0], s1[1]); o[1] = pkbf(s1[2], s1[3]);
        *(u32x2*)(ap + 4) = o;
        o[0] = pkbf(s2[0], s2[1]); o[1] = pkbf(s2[2], s2[3]);
        *(u32x2*)(ap + 8) = o;
        o[0] = pkbf(s3[0], s3[1]); o[1] = pkbf(s3[2], s3[3]);
        *(u32x2*)(ap + 12) = o;
    }

    {
        const int s = tid & 15;
        const int rb = tid >> 4;
        #pragma unroll
        for (int p = 0; p < 4; ++p) {
            int row = p * 16 + rb;
            long gr = n0 + row;
            if (gr >= N_NODES) gr = N_NODES - 1;
            f32x4 v = *(const f32x4*)(x + gr * 64 + s * 4);
            u32x2 o;
            o[0] = pkbf(v[0], v[1]); o[1] = pkbf(v[2], v[3]);
            *(u32x2*)&A[row * LDH + s * 4] = o;
        }
    }
    __syncthreads();

    s16x8 bf1[4][2];
    #pragma unroll
    for (int ks = 0; ks < 4; ++ks)
        #pragma unroll
        for (int nt = 0; nt < 2; ++nt) {
            int n = 32 * w + nt * 16 + l15;
            bf1[ks][nt] = *(const s16x8*)(W1p + ((size_t)(ks * 128 + n) * 4 + l4) * 8);
        }
    f32x4 acc[4][2] = {};
    #pragma unroll
    for (int ks = 0; ks < 4; ++ks) {
        #pragma unroll
        for (int mt = 0; mt < 4; ++mt) {
            s16x8 a = *(const s16x8*)&A[(mt * 16 + l15) * LDH + ks * 32 + l4 * 8];
            #pragma unroll
            for (int nt = 0; nt < 2; ++nt)
                acc[mt][nt] = mfma16(a, bf1[ks][nt], acc[mt][nt]);
        }
    }
    __syncthreads();

    #pragma unroll
    for (int nt = 0; nt < 2; ++nt) {
        int n = 32 * w + nt * 16 + l15;
        float b = nb1[n];
        #pragma unroll
        for (int mt = 0; mt < 4; ++mt) {
            float v0 = fmaxf(acc[mt][nt][0] + b, 0.f);
            float v1 = fmaxf(acc[mt][nt][1] + b, 0.f);
            float v2 = fmaxf(acc[mt][nt][2] + b, 0.f);
            float v3 = fmaxf(acc[mt][nt][3] + b, 0.f);
            unsigned w0 = pkbf(v0, v1), w1 = pkbf(v2, v3);
            int r0 = mt * 16 + l4 * 4;
            Hs[(r0 + 0) * LDH + n] = (u16)w0;
            Hs[(r0 + 1) * LDH + n] = (u16)(w0 >> 16);
            Hs[(r0 + 2) * LDH + n] = (u16)w1;
            Hs[(r0 + 3) * LDH + n] = (u16)(w1 >> 16);
        }
    }
    __syncthreads();

    s16x8 bf2v[4];
    #pragma unroll
    for (int ks = 0; ks < 4; ++ks)
        bf2v[ks] = *(const s16x8*)(W2p + ((size_t)(ks * 64 + 16 * w + l15) * 4 + l4) * 8);
    f32x4 acc2[4] = {};
    #pragma unroll
    for (int ks = 0; ks < 4; ++ks) {
        #pragma unroll
        for (int mt = 0; mt < 4; ++mt) {
            s16x8 a = *(const s16x8*)&Hs[(mt * 16 + l15) * LDH + ks * 32 + l4 * 8];
            acc2[mt] = mfma16(a, bf2v[ks], acc2[mt]);
        }
    }
    __syncthreads();

    {
        int n = 16 * w + l15;
        float b = nb2[n];
        #pragma unroll
        for (int mt = 0; mt < 4; ++mt)
            #pragma unroll
            for (int r = 0; r < 4; ++r)
                C2[(mt * 16 + l4 * 4 + r) * LDC + n] = acc2[mt][r] + b;
    }
    __syncthreads();

    {
        const float* cp = &C2[lrow * LDC + lq * 16];
        float vv[16];
        #pragma unroll
        for (int i = 0; i < 4; ++i) {
            f32x4 t = *(const f32x4*)(cp + i * 4);
            vv[i * 4 + 0] = t[0]; vv[i * 4 + 1] = t[1];
            vv[i * 4 + 2] = t[2]; vv[i * 4 + 3] = t[3];
        }
        float s = 0.f, ss = 0.f;
        #pragma unroll
        for (int i = 0; i < 16; ++i) { s += vv[i]; ss += vv[i] * vv[i]; }
        s  += __shfl_xor(s, 1);  s  += __shfl_xor(s, 2);
        ss += __shfl_xor(ss, 1); ss += __shfl_xor(ss, 2);
        const float mu = s * (1.0f / 64.0f);
        const float var = ss * (1.0f / 64.0f) - mu * mu;
        const float rs = rsqrtf(var + 1e-5f);
        const long gnode = n0 + lrow;
        if (gnode < N_NODES) {
            const float* rp = x + gnode * 64 + lq * 16;
            float* op = out_x + gnode * 64 + lq * 16;
            #pragma unroll
            for (int i4 = 0; i4 < 4; ++i4) {
                f32x4 res = *(const f32x4*)(rp + i4 * 4);
                f32x4 o;
                #pragma unroll
                for (int j = 0; j < 4; ++j) {
                    const int c = lq * 16 + i4 * 4 + j;
                    o[j] = (vv[i4 * 4 + j] - mu) * rs * ng[c] + nbt[c] + res[j];
                }
                *(f32x4*)(op + i4 * 4) = o;
            }
        }
    }
}

extern "C" void kernel_launch(void* const* d_in, const int* in_sizes, int n_in,
                              void* d_out, int out_size, void* d_ws, size_t ws_size,
                              hipStream_t stream) {
    const float* x   = (const float*)d_in[0];
    const float* ea  = (const float*)d_in[1];
    const void*  ei  = d_in[2];
    const float* eW1 = (const float*)d_in[3];
    const float* eb1 = (const float*)d_in[4];
    const float* eW2 = (const float*)d_in[5];
    const float* eb2 = (const float*)d_in[6];
    const float* eg  = (const float*)d_in[7];
    const float* ebt = (const float*)d_in[8];
    const float* nW1 = (const float*)d_in[9];
    const float* nb1 = (const float*)d_in[10];
    const float* nW2 = (const float*)d_in[11];
    const float* nb2 = (const float*)d_in[12];
    const float* ng  = (const float*)d_in[13];
    const float* nbt = (const float*)d_in[14];

    float* out   = (float*)d_out;
    float* out_x = out;                            // [100000, 64]
    float* out_e = out + (size_t)N_NODES * 64;     // [1600000, 64]

    // ws layout: packed weights 114688 B | flag 4 B | pad |
    //            cnt 400000 B | pad | idx 100000*CAP*4 B   (~24.5 MB total)
    u16* W1p   = (u16*)d_ws;
    u16* W2p   = W1p + 24576;
    u16* nW1p  = W2p + 8192;
    u16* nW2p  = nW1p + 16384;
    int* flag  = (int*)((char*)d_ws + 114688);
    int* cnt   = (int*)((char*)d_ws + 114944);
    int* idx   = (int*)((char*)d_ws + 515072);

    hipMemsetAsync(cnt, 0, (size_t)N_NODES * sizeof(int), stream);
    pack_w<<<225, 256, 0, stream>>>(eW1, eW2, nW1, nW2, W1p, W2p, nW1p, nW2p,
                                    (const int*)ei, flag);
    edge_kernel<<<N_EDGES / (64 * T_TILES), 256, 0, stream>>>(
        x, ea, ei, flag, W1p, eb1, W2p, eb2, eg, ebt, out_e, cnt, idx);
    node_kernel<<<(N_NODES + 63) / 64, 256, 0, stream>>>(x, out_e, cnt, idx,
                                                         nW1p, nb1, nW2p, nb2,
                                                         ng, nbt, out_x);
}

// Round 14
// 522.176 us; speedup vs baseline: 1.7481x; 1.6488x over previous
//
#include <hip/hip_runtime.h>

#define N_NODES 100000
#define N_EDGES 1600000
#define CAP 60            // per-node edge-list capacity; P(deg>60) ~ 1e-10

typedef unsigned short u16;
typedef short s16x8 __attribute__((ext_vector_type(8)));
typedef float f32x4 __attribute__((ext_vector_type(4)));
typedef unsigned u32x2 __attribute__((ext_vector_type(2)));
typedef unsigned u32x4 __attribute__((ext_vector_type(4)));

__device__ __forceinline__ u16 f2bf(float f) {   // software RNE, proven R2-R13
    union { float f; unsigned int i; } c;
    c.f = f;
    unsigned int u = c.i;
    return (u16)((u + 0x7fffu + ((u >> 16) & 1u)) >> 16);
}

// packed f32x2 -> bf16x2 (software RNE). Failure log: hand-written
// v_cvt_pk_bf16_f32 asm corrupted values (R5); NT loads regressed (R8);
// raw s_barrier pipeline raced (R11); cross-phase register prefetch spilled
// twice (R7 cap-spill, R12/R13 allocator-heuristic spill at VGPR=84 despite
// a 170 cap). Structure below = R9's un-pipelined edge, the proven optimum.
__device__ __forceinline__ unsigned pkbf(float lo, float hi) {
    return (unsigned)f2bf(lo) | ((unsigned)f2bf(hi) << 16);
}

__device__ __forceinline__ f32x4 mfma16(s16x8 a, s16x8 b, f32x4 c) {
    return __builtin_amdgcn_mfma_f32_16x16x32_bf16(a, b, c, 0, 0, 0);
}

// ---------------------------------------------------------------------------
// Weight repack (f32 -> bf16) into MFMA B-fragment order; block 224 instead
// runs the edge_index width detection (int64 => odd int32 words all zero).
// (Fusion saved a dispatch — R12-proven.)
// ---------------------------------------------------------------------------
__global__ __launch_bounds__(256) void pack_w(
    const float* __restrict__ eW1, const float* __restrict__ eW2,
    const float* __restrict__ nW1, const float* __restrict__ nW2,
    u16* __restrict__ W1p, u16* __restrict__ W2p,
    u16* __restrict__ nW1p, u16* __restrict__ nW2p,
    const int* __restrict__ eidx, int* __restrict__ flag)
{
    if (blockIdx.x == 224) {                       // fused detect_idx
        __shared__ int snz;
        const int tid = threadIdx.x;
        if (tid == 0) snz = 0;
        __syncthreads();
        int nz = 0;
        #pragma unroll
        for (int k = 0; k < 8; ++k) {
            long pos = 1 + 2 * ((long)tid * 781 + k * 97);
            if (pos < 2L * N_EDGES) nz |= (eidx[pos] != 0);
        }
        if (nz) snz = 1;
        __syncthreads();
        if (tid == 0) *flag = snz ? 0 : 1;
        return;
    }
    int t = blockIdx.x * 256 + threadIdx.x;
    if (t < 24576) {                               // eW1 [192][128]
        int j = t & 7, kg = (t >> 3) & 3, n = (t >> 5) & 127, ks = t >> 12;
        W1p[t] = f2bf(eW1[(ks * 32 + kg * 8 + j) * 128 + n]);
    } else if (t < 24576 + 8192) {                 // eW2 [128][64]
        int u = t - 24576;
        int j = u & 7, kg = (u >> 3) & 3, n = (u >> 5) & 63, ks = u >> 11;
        W2p[u] = f2bf(eW2[(ks * 32 + kg * 8 + j) * 64 + n]);
    } else if (t < 24576 + 8192 + 16384) {         // nW1 [128][128]
        int u = t - (24576 + 8192);
        int j = u & 7, kg = (u >> 3) & 3, n = (u >> 5) & 127, ks = u >> 12;
        nW1p[u] = f2bf(nW1[(ks * 32 + kg * 8 + j) * 128 + n]);
    } else if (t < 24576 + 8192 + 16384 + 8192) {  // nW2 [128][64]
        int u = t - (24576 + 8192 + 16384);
        int j = u & 7, kg = (u >> 3) & 3, n = (u >> 5) & 63, ks = u >> 11;
        nW2p[u] = f2bf(nW2[(ks * 32 + kg * 8 + j) * 64 + n]);
    }
}

#define LDA1 200   // 64x192 bf16 input tile row stride (400B = 4-bank step)
#define LDH  136   // hidden tile row stride (overlays A1/A)
#define LDC  68    // f32 pre-LN tile row stride (overlays A1/A)

// ---------------------------------------------------------------------------
// Edge update: R9 structure exactly (64 edges/block, 256 threads, 26.1KB LDS,
// 6 blocks/CU, Hs/C2 overlay A1, residual in 8 bf16-pair regs) + fused CSR
// build: the dst-index loaders (tid 64..127) do the atomicAdd+idx write
// inline, killing the build_csr dispatch and its 25.6MB re-read (R12-proven).
// ---------------------------------------------------------------------------
__global__ __launch_bounds__(256, 6) void edge_kernel(
    const float* __restrict__ x, const float* __restrict__ ea,
    const void* __restrict__ eidx_raw, const int* __restrict__ flag64,
    const u16* __restrict__ W1p, const float* __restrict__ eb1,
    const u16* __restrict__ W2p, const float* __restrict__ eb2,
    const float* __restrict__ eg, const float* __restrict__ ebt,
    float* __restrict__ out_e, int* __restrict__ cnt, int* __restrict__ idx)
{
    __shared__ __align__(16) u16 A1[64 * LDA1];   // 25.6KB; Hs & C2 overlay
    __shared__ int s_src[64];
    __shared__ int s_dst[64];
    u16* Hs   = A1;
    float* C2 = (float*)A1;

    const int tid = threadIdx.x;
    const int lane = tid & 63;
    const int w = tid >> 6;          // wave 0..3, owns GEMM1 cols 32w..32w+31
    const int l15 = lane & 15;
    const int l4 = lane >> 4;
    const long e0 = (long)blockIdx.x * 64;
    const int f64 = *flag64;

    // ---- residual slice (read-once): overlaps idx load + staging ----
    const int lrow = tid >> 2;       // 0..63
    const int lq = tid & 3;
    const float* rp = ea + (e0 + lrow) * 64 + lq * 16;
    f32x4 rv0 = *(const f32x4*)(rp);
    f32x4 rv1 = *(const f32x4*)(rp + 4);
    f32x4 rv2 = *(const f32x4*)(rp + 8);
    f32x4 rv3 = *(const f32x4*)(rp + 12);

    if (tid < 64) {
        int v = f64 ? (int)((const long long*)eidx_raw)[e0 + tid]
                    : ((const int*)eidx_raw)[e0 + tid];
        s_src[tid] = min(max(v, 0), N_NODES - 1);
    } else if (tid < 128) {
        int t = tid - 64;
        int v = f64 ? (int)((const long long*)eidx_raw)[(long)N_EDGES + e0 + t]
                    : ((const int*)eidx_raw)[(long)N_EDGES + e0 + t];
        v = min(max(v, 0), N_NODES - 1);
        s_dst[t] = v;
        // fused CSR build: one atomic + one store per edge
        int slot = atomicAdd(&cnt[v], 1);
        if (slot < CAP) idx[(long)v * CAP + slot] = (int)(e0 + t);
    }
    __syncthreads();

    // ---- stage x segs: 128 (edge,seg) chunks of 64 f32; 16 lanes x f32x4 ----
    {
        const int s = tid & 15;
        const int cb = tid >> 4;     // 0..15
        #pragma unroll
        for (int p = 0; p < 8; ++p) {
            int chunk = p * 16 + cb;
            int i = chunk >> 1;
            int seg = chunk & 1;
            const float* srcp = x + (long)(seg ? s_dst[i] : s_src[i]) * 64;
            f32x4 v = *(const f32x4*)(srcp + s * 4);
            u32x2 wv;
            wv[0] = pkbf(v[0], v[1]); wv[1] = pkbf(v[2], v[3]);
            *(u32x2*)&A1[i * LDA1 + seg * 64 + s * 4] = wv;
        }
    }
    // ---- pack residual to bf16 pairs; write A1 ea cols; keep in regs ----
    unsigned prs[8];
    prs[0] = pkbf(rv0[0], rv0[1]); prs[1] = pkbf(rv0[2], rv0[3]);
    prs[2] = pkbf(rv1[0], rv1[1]); prs[3] = pkbf(rv1[2], rv1[3]);
    prs[4] = pkbf(rv2[0], rv2[1]); prs[5] = pkbf(rv2[2], rv2[3]);
    prs[6] = pkbf(rv3[0], rv3[1]); prs[7] = pkbf(rv3[2], rv3[3]);
    {
        u16* ap = &A1[lrow * LDA1 + 128 + lq * 16];
        u32x4 w0 = {prs[0], prs[1], prs[2], prs[3]};
        u32x4 w1 = {prs[4], prs[5], prs[6], prs[7]};
        *(u32x4*)(ap) = w0;
        *(u32x4*)(ap + 8) = w1;
    }
    __syncthreads();

    // ---- GEMM1: [64x192] @ [192x128], wave w owns cols 32w..32w+31 ----
    s16x8 bf1[6][2];
    #pragma unroll
    for (int ks = 0; ks < 6; ++ks)
        #pragma unroll
        for (int nt = 0; nt < 2; ++nt) {
            int n = 32 * w + nt * 16 + l15;
            bf1[ks][nt] = *(const s16x8*)(W1p + ((size_t)(ks * 128 + n) * 4 + l4) * 8);
        }
    f32x4 acc[4][2] = {};
    #pragma unroll
    for (int ks = 0; ks < 6; ++ks) {
        #pragma unroll
        for (int mt = 0; mt < 4; ++mt) {
            s16x8 a = *(const s16x8*)&A1[(mt * 16 + l15) * LDA1 + ks * 32 + l4 * 8];
            #pragma unroll
            for (int nt = 0; nt < 2; ++nt)
                acc[mt][nt] = mfma16(a, bf1[ks][nt], acc[mt][nt]);
        }
    }
    __syncthreads();   // all A1 reads done; overlay writable

    // bias + relu -> Hs (bf16, overlays A1)
    #pragma unroll
    for (int nt = 0; nt < 2; ++nt) {
        int n = 32 * w + nt * 16 + l15;
        float b = eb1[n];
        #pragma unroll
        for (int mt = 0; mt < 4; ++mt) {
            float v0 = fmaxf(acc[mt][nt][0] + b, 0.f);
            float v1 = fmaxf(acc[mt][nt][1] + b, 0.f);
            float v2 = fmaxf(acc[mt][nt][2] + b, 0.f);
            float v3 = fmaxf(acc[mt][nt][3] + b, 0.f);
            unsigned w0 = pkbf(v0, v1), w1 = pkbf(v2, v3);
            int r0 = mt * 16 + l4 * 4;
            Hs[(r0 + 0) * LDH + n] = (u16)w0;
            Hs[(r0 + 1) * LDH + n] = (u16)(w0 >> 16);
            Hs[(r0 + 2) * LDH + n] = (u16)w1;
            Hs[(r0 + 3) * LDH + n] = (u16)(w1 >> 16);
        }
    }
    __syncthreads();

    // ---- GEMM2: [64x128] @ [128x64], wave w owns cols 16w..16w+15 ----
    s16x8 bf2v[4];
    #pragma unroll
    for (int ks = 0; ks < 4; ++ks)
        bf2v[ks] = *(const s16x8*)(W2p + ((size_t)(ks * 64 + 16 * w + l15) * 4 + l4) * 8);
    f32x4 acc2[4] = {};
    #pragma unroll
    for (int ks = 0; ks < 4; ++ks) {
        #pragma unroll
        for (int mt = 0; mt < 4; ++mt) {
            s16x8 a = *(const s16x8*)&Hs[(mt * 16 + l15) * LDH + ks * 32 + l4 * 8];
            acc2[mt] = mfma16(a, bf2v[ks], acc2[mt]);
        }
    }
    __syncthreads();   // all Hs reads done; C2 may overwrite

    {
        int n = 16 * w + l15;
        float b = eb2[n];
        #pragma unroll
        for (int mt = 0; mt < 4; ++mt)
            #pragma unroll
            for (int r = 0; r < 4; ++r)
                C2[(mt * 16 + l4 * 4 + r) * LDC + n] = acc2[mt][r] + b;
    }
    __syncthreads();

    // ---- LayerNorm + residual(regs) + store ----
    {
        const float* cp = &C2[lrow * LDC + lq * 16];
        float vv[16];
        #pragma unroll
        for (int i = 0; i < 4; ++i) {
            f32x4 t = *(const f32x4*)(cp + i * 4);
            vv[i * 4 + 0] = t[0]; vv[i * 4 + 1] = t[1];
            vv[i * 4 + 2] = t[2]; vv[i * 4 + 3] = t[3];
        }
        float s = 0.f, ss = 0.f;
        #pragma unroll
        for (int i = 0; i < 16; ++i) { s += vv[i]; ss += vv[i] * vv[i]; }
        s  += __shfl_xor(s, 1);  s  += __shfl_xor(s, 2);
        ss += __shfl_xor(ss, 1); ss += __shfl_xor(ss, 2);
        const float mu = s * (1.0f / 64.0f);
        const float var = ss * (1.0f / 64.0f) - mu * mu;
        const float rs = rsqrtf(var + 1e-5f);
        float* op = out_e + (e0 + lrow) * 64 + lq * 16;
        #pragma unroll
        for (int i4 = 0; i4 < 4; ++i4) {
            f32x4 o;
            #pragma unroll
            for (int j2 = 0; j2 < 2; ++j2) {
                union { unsigned u; float f; } lo, hi;
                lo.u = prs[i4 * 2 + j2] << 16;
                hi.u = prs[i4 * 2 + j2] & 0xffff0000u;
                const int c0 = lq * 16 + i4 * 4 + j2 * 2;
                o[j2 * 2 + 0] = (vv[i4 * 4 + j2 * 2 + 0] - mu) * rs * eg[c0] + ebt[c0] + lo.f;
                o[j2 * 2 + 1] = (vv[i4 * 4 + j2 * 2 + 1] - mu) * rs * eg[c0 + 1] + ebt[c0 + 1] + hi.f;
            }
            *(f32x4*)(op + i4 * 4) = o;
        }
    }
}

// ---------------------------------------------------------------------------
// Node update: 64 nodes/block, 256 threads, single LDS buffer (Hs/C2 overlay
// A) -> 17.4KB -> 6 blocks/CU. CSR gather from out_e (plain loads; NT
// regressed in R8). Unchanged from R9.
// ---------------------------------------------------------------------------
__global__ __launch_bounds__(256, 6) void node_kernel(
    const float* __restrict__ x, const float* __restrict__ out_e,
    const int* __restrict__ cnt, const int* __restrict__ idx,
    const u16* __restrict__ W1p, const float* __restrict__ nb1,
    const u16* __restrict__ W2p, const float* __restrict__ nb2,
    const float* __restrict__ ng, const float* __restrict__ nbt,
    float* __restrict__ out_x)
{
    __shared__ __align__(16) u16 A[64 * LDH];    // Hs and C2 overlay
    u16* Hs   = A;
    float* C2 = (float*)A;

    const int tid = threadIdx.x;
    const int lane = tid & 63;
    const int w = tid >> 6;
    const int l15 = lane & 15;
    const int l4 = lane >> 4;
    const int n0 = blockIdx.x * 64;

    const int lrow = tid >> 2;
    const int lq = tid & 3;
    {
        int n = n0 + lrow;
        if (n >= N_NODES) n = N_NODES - 1;
        int c = cnt[n];
        if (c > CAP) c = CAP;
        const int* ip = idx + (long)n * CAP;
        f32x4 s0 = {}, s1 = {}, s2 = {}, s3 = {};
        int j = 0;
        for (; j + 4 <= c; j += 4) {
            int ev0 = ip[j], ev1 = ip[j + 1], ev2 = ip[j + 2], ev3 = ip[j + 3];
            const float* p0 = out_e + (long)ev0 * 64 + lq * 16;
            const float* p1 = out_e + (long)ev1 * 64 + lq * 16;
            const float* p2 = out_e + (long)ev2 * 64 + lq * 16;
            const float* p3 = out_e + (long)ev3 * 64 + lq * 16;
            f32x4 a00 = *(const f32x4*)(p0);     f32x4 a01 = *(const f32x4*)(p0 + 4);
            f32x4 a02 = *(const f32x4*)(p0 + 8); f32x4 a03 = *(const f32x4*)(p0 + 12);
            f32x4 a10 = *(const f32x4*)(p1);     f32x4 a11 = *(const f32x4*)(p1 + 4);
            f32x4 a12 = *(const f32x4*)(p1 + 8); f32x4 a13 = *(const f32x4*)(p1 + 12);
            f32x4 a20 = *(const f32x4*)(p2);     f32x4 a21 = *(const f32x4*)(p2 + 4);
            f32x4 a22 = *(const f32x4*)(p2 + 8); f32x4 a23 = *(const f32x4*)(p2 + 12);
            f32x4 a30 = *(const f32x4*)(p3);     f32x4 a31 = *(const f32x4*)(p3 + 4);
            f32x4 a32 = *(const f32x4*)(p3 + 8); f32x4 a33 = *(const f32x4*)(p3 + 12);
            s0 += a00 + a10 + a20 + a30;
            s1 += a01 + a11 + a21 + a31;
            s2 += a02 + a12 + a22 + a32;
            s3 += a03 + a13 + a23 + a33;
        }
        for (; j < c; ++j) {
            int ev = ip[j];
            const float* p = out_e + (long)ev * 64 + lq * 16;
            s0 += *(const f32x4*)(p);
            s1 += *(const f32x4*)(p + 4);
            s2 += *(const f32x4*)(p + 8);
            s3 += *(const f32x4*)(p + 12);
        }
        u16* ap = &A[lrow * LDH + 64 + lq * 16];
        u32x2 o;
        o[0] = pkbf(s0[0], s0[1]); o[1] = pkbf(s0[2], s0[3]);
        *(u32x2*)(ap) = o;
        o[0] = pkbf(s1[0], s1[1]); o[1] = pkbf(s1[2], s1[3]);
        *(u32x2*)(ap + 4) = o;
        o[0] = pkbf(s2[0], s2[1]); o[1] = pkbf(s2[2], s2[3]);
        *(u32x2*)(ap + 8) = o;
        o[0] = pkbf(s3[0], s3[1]); o[1] = pkbf(s3[2], s3[3]);
        *(u32x2*)(ap + 12) = o;
    }

    {
        const int s = tid & 15;
        const int rb = tid >> 4;
        #pragma unroll
        for (int p = 0; p < 4; ++p) {
            int row = p * 16 + rb;
            long gr = n0 + row;
            if (gr >= N_NODES) gr = N_NODES - 1;
            f32x4 v = *(const f32x4*)(x + gr * 64 + s * 4);
            u32x2 o;
            o[0] = pkbf(v[0], v[1]); o[1] = pkbf(v[2], v[3]);
            *(u32x2*)&A[row * LDH + s * 4] = o;
        }
    }
    __syncthreads();

    s16x8 bf1[4][2];
    #pragma unroll
    for (int ks = 0; ks < 4; ++ks)
        #pragma unroll
        for (int nt = 0; nt < 2; ++nt) {
            int n = 32 * w + nt * 16 + l15;
            bf1[ks][nt] = *(const s16x8*)(W1p + ((size_t)(ks * 128 + n) * 4 + l4) * 8);
        }
    f32x4 acc[4][2] = {};
    #pragma unroll
    for (int ks = 0; ks < 4; ++ks) {
        #pragma unroll
        for (int mt = 0; mt < 4; ++mt) {
            s16x8 a = *(const s16x8*)&A[(mt * 16 + l15) * LDH + ks * 32 + l4 * 8];
            #pragma unroll
            for (int nt = 0; nt < 2; ++nt)
                acc[mt][nt] = mfma16(a, bf1[ks][nt], acc[mt][nt]);
        }
    }
    __syncthreads();

    #pragma unroll
    for (int nt = 0; nt < 2; ++nt) {
        int n = 32 * w + nt * 16 + l15;
        float b = nb1[n];
        #pragma unroll
        for (int mt = 0; mt < 4; ++mt) {
            float v0 = fmaxf(acc[mt][nt][0] + b, 0.f);
            float v1 = fmaxf(acc[mt][nt][1] + b, 0.f);
            float v2 = fmaxf(acc[mt][nt][2] + b, 0.f);
            float v3 = fmaxf(acc[mt][nt][3] + b, 0.f);
            unsigned w0 = pkbf(v0, v1), w1 = pkbf(v2, v3);
            int r0 = mt * 16 + l4 * 4;
            Hs[(r0 + 0) * LDH + n] = (u16)w0;
            Hs[(r0 + 1) * LDH + n] = (u16)(w0 >> 16);
            Hs[(r0 + 2) * LDH + n] = (u16)w1;
            Hs[(r0 + 3) * LDH + n] = (u16)(w1 >> 16);
        }
    }
    __syncthreads();

    s16x8 bf2v[4];
    #pragma unroll
    for (int ks = 0; ks < 4; ++ks)
        bf2v[ks] = *(const s16x8*)(W2p + ((size_t)(ks * 64 + 16 * w + l15) * 4 + l4) * 8);
    f32x4 acc2[4] = {};
    #pragma unroll
    for (int ks = 0; ks < 4; ++ks) {
        #pragma unroll
        for (int mt = 0; mt < 4; ++mt) {
            s16x8 a = *(const s16x8*)&Hs[(mt * 16 + l15) * LDH + ks * 32 + l4 * 8];
            acc2[mt] = mfma16(a, bf2v[ks], acc2[mt]);
        }
    }
    __syncthreads();

    {
        int n = 16 * w + l15;
        float b = nb2[n];
        #pragma unroll
        for (int mt = 0; mt < 4; ++mt)
            #pragma unroll
            for (int r = 0; r < 4; ++r)
                C2[(mt * 16 + l4 * 4 + r) * LDC + n] = acc2[mt][r] + b;
    }
    __syncthreads();

    {
        const float* cp = &C2[lrow * LDC + lq * 16];
        float vv[16];
        #pragma unroll
        for (int i = 0; i < 4; ++i) {
            f32x4 t = *(const f32x4*)(cp + i * 4);
            vv[i * 4 + 0] = t[0]; vv[i * 4 + 1] = t[1];
            vv[i * 4 + 2] = t[2]; vv[i * 4 + 3] = t[3];
        }
        float s = 0.f, ss = 0.f;
        #pragma unroll
        for (int i = 0; i < 16; ++i) { s += vv[i]; ss += vv[i] * vv[i]; }
        s  += __shfl_xor(s, 1);  s  += __shfl_xor(s, 2);
        ss += __shfl_xor(ss, 1); ss += __shfl_xor(ss, 2);
        const float mu = s * (1.0f / 64.0f);
        const float var = ss * (1.0f / 64.0f) - mu * mu;
        const float rs = rsqrtf(var + 1e-5f);
        const long gnode = n0 + lrow;
        if (gnode < N_NODES) {
            const float* rp = x + gnode * 64 + lq * 16;
            float* op = out_x + gnode * 64 + lq * 16;
            #pragma unroll
            for (int i4 = 0; i4 < 4; ++i4) {
                f32x4 res = *(const f32x4*)(rp + i4 * 4);
                f32x4 o;
                #pragma unroll
                for (int j = 0; j < 4; ++j) {
                    const int c = lq * 16 + i4 * 4 + j;
                    o[j] = (vv[i4 * 4 + j] - mu) * rs * ng[c] + nbt[c] + res[j];
                }
                *(f32x4*)(op + i4 * 4) = o;
            }
        }
    }
}

extern "C" void kernel_launch(void* const* d_in, const int* in_sizes, int n_in,
                              void* d_out, int out_size, void* d_ws, size_t ws_size,
                              hipStream_t stream) {
    const float* x   = (const float*)d_in[0];
    const float* ea  = (const float*)d_in[1];
    const void*  ei  = d_in[2];
    const float* eW1 = (const float*)d_in[3];
    const float* eb1 = (const float*)d_in[4];
    const float* eW2 = (const float*)d_in[5];
    const float* eb2 = (const float*)d_in[6];
    const float* eg  = (const float*)d_in[7];
    const float* ebt = (const float*)d_in[8];
    const float* nW1 = (const float*)d_in[9];
    const float* nb1 = (const float*)d_in[10];
    const float* nW2 = (const float*)d_in[11];
    const float* nb2 = (const float*)d_in[12];
    const float* ng  = (const float*)d_in[13];
    const float* nbt = (const float*)d_in[14];

    float* out   = (float*)d_out;
    float* out_x = out;                            // [100000, 64]
    float* out_e = out + (size_t)N_NODES * 64;     // [1600000, 64]

    // ws layout: packed weights 114688 B | flag 4 B | pad |
    //            cnt 400000 B | pad | idx 100000*CAP*4 B   (~24.5 MB total)
    u16* W1p   = (u16*)d_ws;
    u16* W2p   = W1p + 24576;
    u16* nW1p  = W2p + 8192;
    u16* nW2p  = nW1p + 16384;
    int* flag  = (int*)((char*)d_ws + 114688);
    int* cnt   = (int*)((char*)d_ws + 114944);
    int* idx   = (int*)((char*)d_ws + 515072);

    hipMemsetAsync(cnt, 0, (size_t)N_NODES * sizeof(int), stream);
    pack_w<<<225, 256, 0, stream>>>(eW1, eW2, nW1, nW2, W1p, W2p, nW1p, nW2p,
                                    (const int*)ei, flag);
    edge_kernel<<<N_EDGES / 64, 256, 0, stream>>>(x, ea, ei, flag, W1p, eb1,
                                                  W2p, eb2, eg, ebt, out_e,
                                                  cnt, idx);
    node_kernel<<<(N_NODES + 63) / 64, 256, 0, stream>>>(x, out_e, cnt, idx,
                                                         nW1p, nb1, nW2p, nb2,
                                                         ng, nbt, out_x);
}